// Round 1
// baseline (5411.480 us; speedup 1.0000x reference)
//
#include <hip/hip_runtime.h>
#include <hip/hip_bf16.h>
#include <cstddef>

#define NA 50000
#define NP 100000
#define NE 200000

__device__ __forceinline__ float elu_f(float x) {
  return x > 0.0f ? x : expm1f(x);
}

// ---------------- degree counting ----------------
__global__ void count_deg(const int* __restrict__ dst_p, const int* __restrict__ dst_a,
                          float* cnt_p, float* cnt_a) {
  int stride = gridDim.x * blockDim.x;
  for (int e = blockIdx.x * blockDim.x + threadIdx.x; e < 2 * NE; e += stride) {
    if (e < NE) atomicAdd(&cnt_p[dst_p[e]], 1.0f);
    else        atomicAdd(&cnt_a[dst_a[e - NE]], 1.0f);
  }
}

__global__ void invert_cnt(float* c, int n) {
  int i = blockIdx.x * blockDim.x + threadIdx.x;
  if (i < n) c[i] = 1.0f / fmaxf(c[i], 1.0f);
}

// ---------------- weight prep ----------------
// W: [256][K] row-major -> WT: [K][256]
__global__ void transpose_w(const float* __restrict__ W, float* __restrict__ WT, int K) {
  __shared__ float tile[32][33];
  int ktiles = K / 32;
  int bk = blockIdx.x % ktiles;
  int bn = blockIdx.x / ktiles;
  int tx = threadIdx.x % 32, ty = threadIdx.x / 32; // 32x8
  #pragma unroll
  for (int i = 0; i < 4; ++i)
    tile[ty + i * 8][tx] = W[(size_t)(bn * 32 + ty + i * 8) * K + bk * 32 + tx];
  __syncthreads();
  #pragma unroll
  for (int i = 0; i < 4; ++i)
    WT[(size_t)(bk * 32 + ty + i * 8) * 256 + bn * 32 + tx] = tile[tx][ty + i * 8];
}

__global__ void add_bias(const float* __restrict__ a, const float* __restrict__ b,
                         float* __restrict__ o) {
  int i = threadIdx.x;
  o[i] = a[i] + b[i];
}

// ---------------- scatter-mean (sum part) ----------------
template <int D>
__global__ __launch_bounds__(256) void scatter_add(
    const float* __restrict__ feat, const int* __restrict__ src,
    const int* __restrict__ dst, float* agg, int E) {
  int gw = (blockIdx.x * 256 + threadIdx.x) >> 6;
  int lane = threadIdx.x & 63;
  int nw = (gridDim.x * 256) >> 6;
  for (int e = gw; e < E; e += nw) {
    int s = src[e], d = dst[e];
    const float* srow = feat + (size_t)s * D;
    float* drow = agg + (size_t)d * D;
    if (D == 256) {
      float4 v = *(const float4*)(srow + lane * 4);
      atomicAdd(drow + lane * 4 + 0, v.x);
      atomicAdd(drow + lane * 4 + 1, v.y);
      atomicAdd(drow + lane * 4 + 2, v.z);
      atomicAdd(drow + lane * 4 + 3, v.w);
    } else {
      float2 v = *(const float2*)(srow + lane * 2);
      atomicAdd(drow + lane * 2 + 0, v.x);
      atomicAdd(drow + lane * 2 + 1, v.y);
    }
  }
}

// ---------------- fused SAGE update ----------------
// out[i,:] = elu( (agg[i,:]*inv_cnt[i]) @ WT1 + xdst[i,:] @ WT2 + bias )
// WT1: [K1][256], WT2: [K2][256]. out may alias xdst (row-exclusive blocks,
// all reads precede writes).
template <int K1, int K2>
__global__ __launch_bounds__(256) void sage_update(
    const float* __restrict__ agg, const float* __restrict__ inv_cnt,
    const float* xdst, const float* __restrict__ WT1,
    const float* __restrict__ WT2, const float* __restrict__ bias,
    float* out, int M) {
  __shared__ float lds_a[32 * 36];
  __shared__ float lds_b[32 * 256];
  float acc[8][4];
  #pragma unroll
  for (int i = 0; i < 8; ++i)
    acc[i][0] = acc[i][1] = acc[i][2] = acc[i][3] = 0.0f;

  const int t = threadIdx.x;
  const int c = t & 63;   // col group: cols 4c..4c+3
  const int r = t >> 6;   // row base: rows r + 4*rr
  const int row0 = blockIdx.x * 32;
  const int ar = t >> 3;        // A-load row 0..31
  const int ak = (t & 7) * 4;   // A-load k offset
  const int arow = min(row0 + ar, M - 1);
  const float s = inv_cnt[arow];

  // phase 1: scaled agg @ WT1
  for (int k0 = 0; k0 < K1; k0 += 32) {
    __syncthreads();
    float4 av = *(const float4*)(agg + (size_t)arow * K1 + k0 + ak);
    av.x *= s; av.y *= s; av.z *= s; av.w *= s;
    *(float4*)(lds_a + ar * 36 + ak) = av;
    #pragma unroll
    for (int i = 0; i < 8; ++i) {
      int idx = t + i * 256;
      int kk = idx >> 6, c4 = (idx & 63) * 4;
      *(float4*)(lds_b + kk * 256 + c4) =
          *(const float4*)(WT1 + (size_t)(k0 + kk) * 256 + c4);
    }
    __syncthreads();
    #pragma unroll
    for (int k = 0; k < 32; ++k) {
      float4 b = *(const float4*)(lds_b + k * 256 + c * 4);
      #pragma unroll
      for (int rr = 0; rr < 8; ++rr) {
        float a = lds_a[(r + rr * 4) * 36 + k];
        acc[rr][0] = fmaf(a, b.x, acc[rr][0]);
        acc[rr][1] = fmaf(a, b.y, acc[rr][1]);
        acc[rr][2] = fmaf(a, b.z, acc[rr][2]);
        acc[rr][3] = fmaf(a, b.w, acc[rr][3]);
      }
    }
  }
  // phase 2: xdst @ WT2
  for (int k0 = 0; k0 < K2; k0 += 32) {
    __syncthreads();
    float4 av = *(const float4*)(xdst + (size_t)arow * K2 + k0 + ak);
    *(float4*)(lds_a + ar * 36 + ak) = av;
    #pragma unroll
    for (int i = 0; i < 8; ++i) {
      int idx = t + i * 256;
      int kk = idx >> 6, c4 = (idx & 63) * 4;
      *(float4*)(lds_b + kk * 256 + c4) =
          *(const float4*)(WT2 + (size_t)(k0 + kk) * 256 + c4);
    }
    __syncthreads();
    #pragma unroll
    for (int k = 0; k < 32; ++k) {
      float4 b = *(const float4*)(lds_b + k * 256 + c * 4);
      #pragma unroll
      for (int rr = 0; rr < 8; ++rr) {
        float a = lds_a[(r + rr * 4) * 36 + k];
        acc[rr][0] = fmaf(a, b.x, acc[rr][0]);
        acc[rr][1] = fmaf(a, b.y, acc[rr][1]);
        acc[rr][2] = fmaf(a, b.z, acc[rr][2]);
        acc[rr][3] = fmaf(a, b.w, acc[rr][3]);
      }
    }
  }
  // epilogue: bias + ELU + store
  float4 bv = *(const float4*)(bias + c * 4);
  #pragma unroll
  for (int rr = 0; rr < 8; ++rr) {
    int row = row0 + r + rr * 4;
    if (row < M) {
      float4 o;
      o.x = elu_f(acc[rr][0] + bv.x);
      o.y = elu_f(acc[rr][1] + bv.y);
      o.z = elu_f(acc[rr][2] + bv.z);
      o.w = elu_f(acc[rr][3] + bv.w);
      *(float4*)(out + (size_t)row * 256 + c * 4) = o;
    }
  }
}

// ---------------- output projection ----------------
// out[i, 0..9] = author[i,:] @ W_out.T + b_out
__global__ __launch_bounds__(256) void out_proj(const float* __restrict__ author,
                                                const float* __restrict__ W,
                                                const float* __restrict__ b,
                                                float* __restrict__ out, int M) {
  __shared__ float ws[10 * 256];
  __shared__ float bs[10];
  int t = threadIdx.x;
  for (int i = t; i < 2560; i += 256) ws[i] = W[i];
  if (t < 10) bs[t] = b[t];
  __syncthreads();
  int wave = t >> 6, lane = t & 63;
  int row = blockIdx.x * 4 + wave;
  if (row >= M) return;
  float4 a = *(const float4*)(author + (size_t)row * 256 + lane * 4);
  float p[10];
  #pragma unroll
  for (int n = 0; n < 10; ++n) {
    const float* w = ws + n * 256 + lane * 4;
    p[n] = a.x * w[0] + a.y * w[1] + a.z * w[2] + a.w * w[3];
  }
  #pragma unroll
  for (int off = 32; off > 0; off >>= 1) {
    #pragma unroll
    for (int n = 0; n < 10; ++n) p[n] += __shfl_down(p[n], off);
  }
  if (lane == 0) {
    #pragma unroll
    for (int n = 0; n < 10; ++n) out[(size_t)row * 10 + n] = p[n] + bs[n];
  }
}

extern "C" void kernel_launch(void* const* d_in, const int* in_sizes, int n_in,
                              void* d_out, int out_size, void* d_ws, size_t ws_size,
                              hipStream_t stream) {
  const float* x_author = (const float*)d_in[0];
  const float* x_paper  = (const float*)d_in[1];
  const int* ei_a2p = (const int*)d_in[2];
  const int* ei_p2a = (const int*)d_in[3];
  const int* src_ap = ei_a2p;       // author indices
  const int* dst_ap = ei_a2p + NE;  // paper indices
  const int* src_pa = ei_p2a;       // paper indices
  const int* dst_pa = ei_p2a + NE;  // author indices
  const float* Wl0_ap = (const float*)d_in[4];
  const float* bl0_ap = (const float*)d_in[5];
  const float* Wr0_ap = (const float*)d_in[6];
  const float* br0_ap = (const float*)d_in[7];
  const float* Wl0_pa = (const float*)d_in[8];
  const float* bl0_pa = (const float*)d_in[9];
  const float* Wr0_pa = (const float*)d_in[10];
  const float* br0_pa = (const float*)d_in[11];
  const float* Wl_ap = (const float*)d_in[12];
  const float* bl_ap = (const float*)d_in[13];
  const float* Wr_ap = (const float*)d_in[14];
  const float* br_ap = (const float*)d_in[15];
  const float* Wl_pa = (const float*)d_in[16];
  const float* bl_pa = (const float*)d_in[17];
  const float* Wr_pa = (const float*)d_in[18];
  const float* br_pa = (const float*)d_in[19];
  const float* W_out = (const float*)d_in[20];
  const float* b_out = (const float*)d_in[21];
  float* out = (float*)d_out;

  // ---- workspace layout (floats) ----
  float* ws = (float*)d_ws;
  size_t o = 0;
  float* paper  = ws + o; o += (size_t)NP * 256;
  float* author = ws + o; o += (size_t)NA * 256;
  float* agg_p  = ws + o; o += (size_t)NP * 256;
  float* agg_a  = ws + o; o += (size_t)NA * 256;
  float* cnt_p  = ws + o; o += NP;   // becomes inverse counts
  float* cnt_a  = ws + o; o += NA;
  float* wt0_ap_l = ws + o; o += 128 * 256;
  float* wt0_ap_r = ws + o; o += 256 * 256;
  float* wt0_pa_l = ws + o; o += 256 * 256;
  float* wt0_pa_r = ws + o; o += 128 * 256;
  float* wt_ap_l = ws + o; o += 2 * 256 * 256;
  float* wt_ap_r = ws + o; o += 2 * 256 * 256;
  float* wt_pa_l = ws + o; o += 2 * 256 * 256;
  float* wt_pa_r = ws + o; o += 2 * 256 * 256;
  float* bias0_ap = ws + o; o += 256;
  float* bias0_pa = ws + o; o += 256;
  float* bias_ap  = ws + o; o += 2 * 256;
  float* bias_pa  = ws + o; o += 2 * 256;

  // ---- degree counts ----
  hipMemsetAsync(cnt_p, 0, (size_t)(NP + NA) * 4, stream);
  count_deg<<<512, 256, 0, stream>>>(dst_ap, dst_pa, cnt_p, cnt_a);
  invert_cnt<<<(NP + NA + 255) / 256, 256, 0, stream>>>(cnt_p, NP + NA);

  // ---- weight prep: transposes + combined biases ----
  transpose_w<<<32, 256, 0, stream>>>(Wl0_ap, wt0_ap_l, 128);
  transpose_w<<<64, 256, 0, stream>>>(Wr0_ap, wt0_ap_r, 256);
  transpose_w<<<64, 256, 0, stream>>>(Wl0_pa, wt0_pa_l, 256);
  transpose_w<<<32, 256, 0, stream>>>(Wr0_pa, wt0_pa_r, 128);
  for (int l = 0; l < 2; ++l) {
    transpose_w<<<64, 256, 0, stream>>>(Wl_ap + (size_t)l * 65536, wt_ap_l + (size_t)l * 65536, 256);
    transpose_w<<<64, 256, 0, stream>>>(Wr_ap + (size_t)l * 65536, wt_ap_r + (size_t)l * 65536, 256);
    transpose_w<<<64, 256, 0, stream>>>(Wl_pa + (size_t)l * 65536, wt_pa_l + (size_t)l * 65536, 256);
    transpose_w<<<64, 256, 0, stream>>>(Wr_pa + (size_t)l * 65536, wt_pa_r + (size_t)l * 65536, 256);
  }
  add_bias<<<1, 256, 0, stream>>>(bl0_ap, br0_ap, bias0_ap);
  add_bias<<<1, 256, 0, stream>>>(bl0_pa, br0_pa, bias0_pa);
  for (int l = 0; l < 2; ++l) {
    add_bias<<<1, 256, 0, stream>>>(bl_ap + l * 256, br_ap + l * 256, bias_ap + l * 256);
    add_bias<<<1, 256, 0, stream>>>(bl_pa + l * 256, br_pa + l * 256, bias_pa + l * 256);
  }

  // ---- layer 0 (author:128, paper:256 inputs) ----
  hipMemsetAsync(agg_p, 0, (size_t)NP * 128 * 4, stream);
  scatter_add<128><<<2048, 256, 0, stream>>>(x_author, src_ap, dst_ap, agg_p, NE);
  hipMemsetAsync(agg_a, 0, (size_t)NA * 256 * 4, stream);
  scatter_add<256><<<2048, 256, 0, stream>>>(x_paper, src_pa, dst_pa, agg_a, NE);
  sage_update<128, 256><<<NP / 32, 256, 0, stream>>>(
      agg_p, cnt_p, x_paper, wt0_ap_l, wt0_ap_r, bias0_ap, paper, NP);
  sage_update<256, 128><<<(NA + 31) / 32, 256, 0, stream>>>(
      agg_a, cnt_a, x_author, wt0_pa_l, wt0_pa_r, bias0_pa, author, NA);

  // ---- layers 1..2 (hidden 256, in-place updates) ----
  for (int l = 0; l < 2; ++l) {
    hipMemsetAsync(agg_p, 0, (size_t)NP * 256 * 4, stream);
    scatter_add<256><<<2048, 256, 0, stream>>>(author, src_ap, dst_ap, agg_p, NE);
    hipMemsetAsync(agg_a, 0, (size_t)NA * 256 * 4, stream);
    scatter_add<256><<<2048, 256, 0, stream>>>(paper, src_pa, dst_pa, agg_a, NE);
    sage_update<256, 256><<<NP / 32, 256, 0, stream>>>(
        agg_p, cnt_p, paper, wt_ap_l + (size_t)l * 65536, wt_ap_r + (size_t)l * 65536,
        bias_ap + (size_t)l * 256, paper, NP);
    sage_update<256, 256><<<(NA + 31) / 32, 256, 0, stream>>>(
        agg_a, cnt_a, author, wt_pa_l + (size_t)l * 65536, wt_pa_r + (size_t)l * 65536,
        bias_pa + (size_t)l * 256, author, NA);
  }

  // ---- output projection ----
  out_proj<<<(NA + 3) / 4, 256, 0, stream>>>(author, W_out, b_out, out, NA);
}

// Round 2
// 2104.608 us; speedup vs baseline: 2.5713x; 2.5713x over previous
//
#include <hip/hip_runtime.h>
#include <hip/hip_bf16.h>
#include <cstddef>

#define NA 50000
#define NP 100000
#define NE 200000
#define SCAN_CHUNK 1024

__device__ __forceinline__ float elu_f(float x) {
  return x > 0.0f ? x : expm1f(x);
}

// ---------------- degree counting (int) ----------------
__global__ void count_deg_i(const int* __restrict__ dst_p, const int* __restrict__ dst_a,
                            int* cnt_p, int* cnt_a) {
  int i = blockIdx.x * blockDim.x + threadIdx.x;
  if (i < NE) atomicAdd(&cnt_p[dst_p[i]], 1);
  else if (i < 2 * NE) atomicAdd(&cnt_a[dst_a[i - NE]], 1);
}

// ---------------- 3-kernel exclusive scan ----------------
__global__ void block_sums_k(const int* __restrict__ cnt, int* __restrict__ bsums, int n) {
  __shared__ int red[256];
  int t = threadIdx.x;
  int base = blockIdx.x * SCAN_CHUNK + t * 4;
  int s = 0;
  #pragma unroll
  for (int i = 0; i < 4; ++i) {
    int idx = base + i;
    if (idx < n) s += cnt[idx];
  }
  red[t] = s;
  __syncthreads();
  for (int off = 128; off > 0; off >>= 1) {
    if (t < off) red[t] += red[t + off];
    __syncthreads();
  }
  if (t == 0) bsums[blockIdx.x] = red[0];
}

__global__ void scan_bsums_k(int* bsums, int nb) {  // nb <= 256, single block
  __shared__ int tmp[256];
  int t = threadIdx.x;
  int orig = (t < nb) ? bsums[t] : 0;
  tmp[t] = orig;
  __syncthreads();
  for (int off = 1; off < 256; off <<= 1) {
    int u = (t >= off) ? tmp[t - off] : 0;
    __syncthreads();
    tmp[t] += u;
    __syncthreads();
  }
  if (t < nb) bsums[t] = tmp[t] - orig;  // exclusive
}

__global__ void scan_final_k(const int* __restrict__ cnt, const int* __restrict__ bsums,
                             int* __restrict__ row_start, int n, int total) {
  __shared__ int red[256];
  int t = threadIdx.x;
  int base = blockIdx.x * SCAN_CHUNK + t * 4;
  int v[4];
  int s = 0;
  #pragma unroll
  for (int i = 0; i < 4; ++i) {
    int idx = base + i;
    v[i] = (idx < n) ? cnt[idx] : 0;
    s += v[i];
  }
  int orig = s;
  red[t] = s;
  __syncthreads();
  for (int off = 1; off < 256; off <<= 1) {
    int u = (t >= off) ? red[t - off] : 0;
    __syncthreads();
    red[t] += u;
    __syncthreads();
  }
  int excl = red[t] - orig + bsums[blockIdx.x];
  #pragma unroll
  for (int i = 0; i < 4; ++i) {
    int idx = base + i;
    if (idx < n) row_start[idx] = excl;
    excl += v[i];
  }
  if (blockIdx.x == 0 && t == 0) row_start[n] = total;
}

__global__ void csr_fill(const int* __restrict__ src, const int* __restrict__ dst,
                         int* cursor, int* __restrict__ csr_src) {
  int e = blockIdx.x * blockDim.x + threadIdx.x;
  if (e < NE) {
    int p = atomicAdd(&cursor[dst[e]], 1);
    csr_src[p] = src[e];
  }
}

// ---------------- gather-mean: one wave per dst node ----------------
template <int D>
__global__ __launch_bounds__(256) void gather_mean(
    const float* __restrict__ feat, const int* __restrict__ csr_src,
    const int* __restrict__ row_start, float* __restrict__ agg, int n) {
  int node = (blockIdx.x * 256 + threadIdx.x) >> 6;
  int lane = threadIdx.x & 63;
  if (node >= n) return;
  int beg = row_start[node], end = row_start[node + 1];
  if (D == 256) {
    float4 acc = {0.f, 0.f, 0.f, 0.f};
    for (int e = beg; e < end; ++e) {
      int s = csr_src[e];
      float4 v = *(const float4*)(feat + (size_t)s * 256 + lane * 4);
      acc.x += v.x; acc.y += v.y; acc.z += v.z; acc.w += v.w;
    }
    float inv = 1.0f / fmaxf((float)(end - beg), 1.0f);
    acc.x *= inv; acc.y *= inv; acc.z *= inv; acc.w *= inv;
    *(float4*)(agg + (size_t)node * 256 + lane * 4) = acc;
  } else {
    float2 acc = {0.f, 0.f};
    for (int e = beg; e < end; ++e) {
      int s = csr_src[e];
      float2 v = *(const float2*)(feat + (size_t)s * 128 + lane * 2);
      acc.x += v.x; acc.y += v.y;
    }
    float inv = 1.0f / fmaxf((float)(end - beg), 1.0f);
    acc.x *= inv; acc.y *= inv;
    *(float2*)(agg + (size_t)node * 128 + lane * 2) = acc;
  }
}

// ---------------- weight prep ----------------
__global__ void transpose_w(const float* __restrict__ W, float* __restrict__ WT, int K) {
  __shared__ float tile[32][33];
  int ktiles = K / 32;
  int bk = blockIdx.x % ktiles;
  int bn = blockIdx.x / ktiles;
  int tx = threadIdx.x % 32, ty = threadIdx.x / 32;  // 32x8
  #pragma unroll
  for (int i = 0; i < 4; ++i)
    tile[ty + i * 8][tx] = W[(size_t)(bn * 32 + ty + i * 8) * K + bk * 32 + tx];
  __syncthreads();
  #pragma unroll
  for (int i = 0; i < 4; ++i)
    WT[(size_t)(bk * 32 + ty + i * 8) * 256 + bn * 32 + tx] = tile[tx][ty + i * 8];
}

__global__ void add_bias(const float* __restrict__ a, const float* __restrict__ b,
                         float* __restrict__ o) {
  int i = threadIdx.x;
  o[i] = a[i] + b[i];
}

// ---------------- fused SAGE update ----------------
// out[i,:] = elu( agg[i,:] @ WT1 + xdst[i,:] @ WT2 + bias )   (agg is already mean)
template <int K1, int K2>
__global__ __launch_bounds__(256) void sage_update(
    const float* __restrict__ agg, const float* xdst,
    const float* __restrict__ WT1, const float* __restrict__ WT2,
    const float* __restrict__ bias, float* out, int M) {
  __shared__ float lds_a[32 * 36];
  __shared__ float lds_b[32 * 256];
  float acc[8][4];
  #pragma unroll
  for (int i = 0; i < 8; ++i)
    acc[i][0] = acc[i][1] = acc[i][2] = acc[i][3] = 0.0f;

  const int t = threadIdx.x;
  const int c = t & 63;
  const int r = t >> 6;
  const int row0 = blockIdx.x * 32;
  const int ar = t >> 3;
  const int ak = (t & 7) * 4;
  const int arow = min(row0 + ar, M - 1);

  for (int k0 = 0; k0 < K1; k0 += 32) {
    __syncthreads();
    *(float4*)(lds_a + ar * 36 + ak) = *(const float4*)(agg + (size_t)arow * K1 + k0 + ak);
    #pragma unroll
    for (int i = 0; i < 8; ++i) {
      int idx = t + i * 256;
      int kk = idx >> 6, c4 = (idx & 63) * 4;
      *(float4*)(lds_b + kk * 256 + c4) = *(const float4*)(WT1 + (size_t)(k0 + kk) * 256 + c4);
    }
    __syncthreads();
    #pragma unroll
    for (int k = 0; k < 32; ++k) {
      float4 b = *(const float4*)(lds_b + k * 256 + c * 4);
      #pragma unroll
      for (int rr = 0; rr < 8; ++rr) {
        float a = lds_a[(r + rr * 4) * 36 + k];
        acc[rr][0] = fmaf(a, b.x, acc[rr][0]);
        acc[rr][1] = fmaf(a, b.y, acc[rr][1]);
        acc[rr][2] = fmaf(a, b.z, acc[rr][2]);
        acc[rr][3] = fmaf(a, b.w, acc[rr][3]);
      }
    }
  }
  for (int k0 = 0; k0 < K2; k0 += 32) {
    __syncthreads();
    *(float4*)(lds_a + ar * 36 + ak) = *(const float4*)(xdst + (size_t)arow * K2 + k0 + ak);
    #pragma unroll
    for (int i = 0; i < 8; ++i) {
      int idx = t + i * 256;
      int kk = idx >> 6, c4 = (idx & 63) * 4;
      *(float4*)(lds_b + kk * 256 + c4) = *(const float4*)(WT2 + (size_t)(k0 + kk) * 256 + c4);
    }
    __syncthreads();
    #pragma unroll
    for (int k = 0; k < 32; ++k) {
      float4 b = *(const float4*)(lds_b + k * 256 + c * 4);
      #pragma unroll
      for (int rr = 0; rr < 8; ++rr) {
        float a = lds_a[(r + rr * 4) * 36 + k];
        acc[rr][0] = fmaf(a, b.x, acc[rr][0]);
        acc[rr][1] = fmaf(a, b.y, acc[rr][1]);
        acc[rr][2] = fmaf(a, b.z, acc[rr][2]);
        acc[rr][3] = fmaf(a, b.w, acc[rr][3]);
      }
    }
  }
  float4 bv = *(const float4*)(bias + c * 4);
  #pragma unroll
  for (int rr = 0; rr < 8; ++rr) {
    int row = row0 + r + rr * 4;
    if (row < M) {
      float4 o;
      o.x = elu_f(acc[rr][0] + bv.x);
      o.y = elu_f(acc[rr][1] + bv.y);
      o.z = elu_f(acc[rr][2] + bv.z);
      o.w = elu_f(acc[rr][3] + bv.w);
      *(float4*)(out + (size_t)row * 256 + c * 4) = o;
    }
  }
}

// ---------------- output projection ----------------
__global__ __launch_bounds__(256) void out_proj(const float* __restrict__ author,
                                                const float* __restrict__ W,
                                                const float* __restrict__ b,
                                                float* __restrict__ out, int M) {
  __shared__ float ws[10 * 256];
  __shared__ float bs[10];
  int t = threadIdx.x;
  for (int i = t; i < 2560; i += 256) ws[i] = W[i];
  if (t < 10) bs[t] = b[t];
  __syncthreads();
  int wave = t >> 6, lane = t & 63;
  int row = blockIdx.x * 4 + wave;
  if (row >= M) return;
  float4 a = *(const float4*)(author + (size_t)row * 256 + lane * 4);
  float p[10];
  #pragma unroll
  for (int n = 0; n < 10; ++n) {
    const float* w = ws + n * 256 + lane * 4;
    p[n] = a.x * w[0] + a.y * w[1] + a.z * w[2] + a.w * w[3];
  }
  #pragma unroll
  for (int off = 32; off > 0; off >>= 1) {
    #pragma unroll
    for (int n = 0; n < 10; ++n) p[n] += __shfl_down(p[n], off);
  }
  if (lane == 0) {
    #pragma unroll
    for (int n = 0; n < 10; ++n) out[(size_t)row * 10 + n] = p[n] + bs[n];
  }
}

extern "C" void kernel_launch(void* const* d_in, const int* in_sizes, int n_in,
                              void* d_out, int out_size, void* d_ws, size_t ws_size,
                              hipStream_t stream) {
  const float* x_author = (const float*)d_in[0];
  const float* x_paper  = (const float*)d_in[1];
  const int* ei_a2p = (const int*)d_in[2];
  const int* ei_p2a = (const int*)d_in[3];
  const int* src_ap = ei_a2p;       // author indices
  const int* dst_ap = ei_a2p + NE;  // paper indices
  const int* src_pa = ei_p2a;       // paper indices
  const int* dst_pa = ei_p2a + NE;  // author indices
  const float* Wl0_ap = (const float*)d_in[4];
  const float* bl0_ap = (const float*)d_in[5];
  const float* Wr0_ap = (const float*)d_in[6];
  const float* br0_ap = (const float*)d_in[7];
  const float* Wl0_pa = (const float*)d_in[8];
  const float* bl0_pa = (const float*)d_in[9];
  const float* Wr0_pa = (const float*)d_in[10];
  const float* br0_pa = (const float*)d_in[11];
  const float* Wl_ap = (const float*)d_in[12];
  const float* bl_ap = (const float*)d_in[13];
  const float* Wr_ap = (const float*)d_in[14];
  const float* br_ap = (const float*)d_in[15];
  const float* Wl_pa = (const float*)d_in[16];
  const float* bl_pa = (const float*)d_in[17];
  const float* Wr_pa = (const float*)d_in[18];
  const float* br_pa = (const float*)d_in[19];
  const float* W_out = (const float*)d_in[20];
  const float* b_out = (const float*)d_in[21];
  float* out = (float*)d_out;

  // ---- workspace layout ----
  float* ws = (float*)d_ws;
  size_t o = 0;
  float* paper  = ws + o; o += (size_t)NP * 256;
  float* author = ws + o; o += (size_t)NA * 256;
  float* agg_p  = ws + o; o += (size_t)NP * 256;
  float* agg_a  = ws + o; o += (size_t)NA * 256;
  float* wt0_ap_l = ws + o; o += 128 * 256;
  float* wt0_ap_r = ws + o; o += 256 * 256;
  float* wt0_pa_l = ws + o; o += 256 * 256;
  float* wt0_pa_r = ws + o; o += 128 * 256;
  float* wt_ap_l = ws + o; o += 2 * 256 * 256;
  float* wt_ap_r = ws + o; o += 2 * 256 * 256;
  float* wt_pa_l = ws + o; o += 2 * 256 * 256;
  float* wt_pa_r = ws + o; o += 2 * 256 * 256;
  float* bias0_ap = ws + o; o += 256;
  float* bias0_pa = ws + o; o += 256;
  float* bias_ap  = ws + o; o += 2 * 256;
  float* bias_pa  = ws + o; o += 2 * 256;
  int* ib = (int*)(ws + o);
  size_t io = 0;
  int* cnt_p  = ib + io; io += NP;      // cnt_p, cnt_a contiguous for one memset
  int* cnt_a  = ib + io; io += NA;
  int* rs_p   = ib + io; io += NP + 1;  // row_start (paper dst, a2p edges)
  int* rs_a   = ib + io; io += NA + 1;  // row_start (author dst, p2a edges)
  int* cur_p  = ib + io; io += NP;
  int* cur_a  = ib + io; io += NA;
  int* csrc_p = ib + io; io += NE;      // author srcs grouped by paper dst
  int* csrc_a = ib + io; io += NE;      // paper srcs grouped by author dst
  int* bsum_p = ib + io; io += 128;
  int* bsum_a = ib + io; io += 128;

  const int NBP = (NP + SCAN_CHUNK - 1) / SCAN_CHUNK;  // 98
  const int NBA = (NA + SCAN_CHUNK - 1) / SCAN_CHUNK;  // 49

  // ---- CSR build (once, reused by all 3 layers) ----
  hipMemsetAsync(cnt_p, 0, (size_t)(NP + NA) * 4, stream);
  count_deg_i<<<(2 * NE + 255) / 256, 256, 0, stream>>>(dst_ap, dst_pa, cnt_p, cnt_a);
  block_sums_k<<<NBP, 256, 0, stream>>>(cnt_p, bsum_p, NP);
  block_sums_k<<<NBA, 256, 0, stream>>>(cnt_a, bsum_a, NA);
  scan_bsums_k<<<1, 256, 0, stream>>>(bsum_p, NBP);
  scan_bsums_k<<<1, 256, 0, stream>>>(bsum_a, NBA);
  scan_final_k<<<NBP, 256, 0, stream>>>(cnt_p, bsum_p, rs_p, NP, NE);
  scan_final_k<<<NBA, 256, 0, stream>>>(cnt_a, bsum_a, rs_a, NA, NE);
  hipMemcpyAsync(cur_p, rs_p, (size_t)NP * 4, hipMemcpyDeviceToDevice, stream);
  hipMemcpyAsync(cur_a, rs_a, (size_t)NA * 4, hipMemcpyDeviceToDevice, stream);
  csr_fill<<<(NE + 255) / 256, 256, 0, stream>>>(src_ap, dst_ap, cur_p, csrc_p);
  csr_fill<<<(NE + 255) / 256, 256, 0, stream>>>(src_pa, dst_pa, cur_a, csrc_a);

  // ---- weight prep ----
  transpose_w<<<32, 256, 0, stream>>>(Wl0_ap, wt0_ap_l, 128);
  transpose_w<<<64, 256, 0, stream>>>(Wr0_ap, wt0_ap_r, 256);
  transpose_w<<<64, 256, 0, stream>>>(Wl0_pa, wt0_pa_l, 256);
  transpose_w<<<32, 256, 0, stream>>>(Wr0_pa, wt0_pa_r, 128);
  for (int l = 0; l < 2; ++l) {
    transpose_w<<<64, 256, 0, stream>>>(Wl_ap + (size_t)l * 65536, wt_ap_l + (size_t)l * 65536, 256);
    transpose_w<<<64, 256, 0, stream>>>(Wr_ap + (size_t)l * 65536, wt_ap_r + (size_t)l * 65536, 256);
    transpose_w<<<64, 256, 0, stream>>>(Wl_pa + (size_t)l * 65536, wt_pa_l + (size_t)l * 65536, 256);
    transpose_w<<<64, 256, 0, stream>>>(Wr_pa + (size_t)l * 65536, wt_pa_r + (size_t)l * 65536, 256);
  }
  add_bias<<<1, 256, 0, stream>>>(bl0_ap, br0_ap, bias0_ap);
  add_bias<<<1, 256, 0, stream>>>(bl0_pa, br0_pa, bias0_pa);
  for (int l = 0; l < 2; ++l) {
    add_bias<<<1, 256, 0, stream>>>(bl_ap + l * 256, br_ap + l * 256, bias_ap + l * 256);
    add_bias<<<1, 256, 0, stream>>>(bl_pa + l * 256, br_pa + l * 256, bias_pa + l * 256);
  }

  // ---- layer 0 ----
  gather_mean<128><<<(NP * 64 + 255) / 256, 256, 0, stream>>>(x_author, csrc_p, rs_p, agg_p, NP);
  gather_mean<256><<<(NA * 64 + 255) / 256, 256, 0, stream>>>(x_paper, csrc_a, rs_a, agg_a, NA);
  sage_update<128, 256><<<NP / 32, 256, 0, stream>>>(
      agg_p, x_paper, wt0_ap_l, wt0_ap_r, bias0_ap, paper, NP);
  sage_update<256, 128><<<(NA + 31) / 32, 256, 0, stream>>>(
      agg_a, x_author, wt0_pa_l, wt0_pa_r, bias0_pa, author, NA);

  // ---- layers 1..2 (both gathers BEFORE in-place updates) ----
  for (int l = 0; l < 2; ++l) {
    gather_mean<256><<<(NP * 64 + 255) / 256, 256, 0, stream>>>(author, csrc_p, rs_p, agg_p, NP);
    gather_mean<256><<<(NA * 64 + 255) / 256, 256, 0, stream>>>(paper, csrc_a, rs_a, agg_a, NA);
    sage_update<256, 256><<<NP / 32, 256, 0, stream>>>(
        agg_p, paper, wt_ap_l + (size_t)l * 65536, wt_ap_r + (size_t)l * 65536,
        bias_ap + (size_t)l * 256, paper, NP);
    sage_update<256, 256><<<(NA + 31) / 32, 256, 0, stream>>>(
        agg_a, author, wt_pa_l + (size_t)l * 65536, wt_pa_r + (size_t)l * 65536,
        bias_pa + (size_t)l * 256, author, NA);
  }

  // ---- output projection ----
  out_proj<<<(NA + 3) / 4, 256, 0, stream>>>(author, W_out, b_out, out, NA);
}

// Round 3
// 1105.443 us; speedup vs baseline: 4.8953x; 1.9039x over previous
//
#include <hip/hip_runtime.h>
#include <hip/hip_bf16.h>
#include <cstddef>

#define NA 50000
#define NP 100000
#define NE 200000
#define SCAN_CHUNK 1024

typedef unsigned short u16;
typedef unsigned int u32;
typedef short v8s __attribute__((ext_vector_type(8)));
typedef float f32x4 __attribute__((ext_vector_type(4)));

__device__ __forceinline__ float elu_f(float x) {
  return x > 0.0f ? x : expm1f(x);
}
__device__ __forceinline__ u16 f2bf(float x) {
  u32 u = __float_as_uint(x);
  return (u16)((u + 0x7fffu + ((u >> 16) & 1u)) >> 16);
}
__device__ __forceinline__ float bf2f(u16 h) {
  return __uint_as_float(((u32)h) << 16);
}
__device__ __forceinline__ u32 pk2(float a, float b) {
  return (u32)f2bf(a) | ((u32)f2bf(b) << 16);
}

// ---------------- degree counting (int) ----------------
__global__ void count_deg_i(const int* __restrict__ dst_p, const int* __restrict__ dst_a,
                            int* cnt_p, int* cnt_a) {
  int i = blockIdx.x * blockDim.x + threadIdx.x;
  if (i < NE) atomicAdd(&cnt_p[dst_p[i]], 1);
  else if (i < 2 * NE) atomicAdd(&cnt_a[dst_a[i - NE]], 1);
}

// ---------------- 3-kernel exclusive scan ----------------
__global__ void block_sums_k(const int* __restrict__ cnt, int* __restrict__ bsums, int n) {
  __shared__ int red[256];
  int t = threadIdx.x;
  int base = blockIdx.x * SCAN_CHUNK + t * 4;
  int s = 0;
  #pragma unroll
  for (int i = 0; i < 4; ++i) {
    int idx = base + i;
    if (idx < n) s += cnt[idx];
  }
  red[t] = s;
  __syncthreads();
  for (int off = 128; off > 0; off >>= 1) {
    if (t < off) red[t] += red[t + off];
    __syncthreads();
  }
  if (t == 0) bsums[blockIdx.x] = red[0];
}

__global__ void scan_bsums_k(int* bsums, int nb) {  // nb <= 256, single block
  __shared__ int tmp[256];
  int t = threadIdx.x;
  int orig = (t < nb) ? bsums[t] : 0;
  tmp[t] = orig;
  __syncthreads();
  for (int off = 1; off < 256; off <<= 1) {
    int u = (t >= off) ? tmp[t - off] : 0;
    __syncthreads();
    tmp[t] += u;
    __syncthreads();
  }
  if (t < nb) bsums[t] = tmp[t] - orig;  // exclusive
}

__global__ void scan_final_k(const int* __restrict__ cnt, const int* __restrict__ bsums,
                             int* __restrict__ row_start, int n, int total) {
  __shared__ int red[256];
  int t = threadIdx.x;
  int base = blockIdx.x * SCAN_CHUNK + t * 4;
  int v[4];
  int s = 0;
  #pragma unroll
  for (int i = 0; i < 4; ++i) {
    int idx = base + i;
    v[i] = (idx < n) ? cnt[idx] : 0;
    s += v[i];
  }
  int orig = s;
  red[t] = s;
  __syncthreads();
  for (int off = 1; off < 256; off <<= 1) {
    int u = (t >= off) ? red[t - off] : 0;
    __syncthreads();
    red[t] += u;
    __syncthreads();
  }
  int excl = red[t] - orig + bsums[blockIdx.x];
  #pragma unroll
  for (int i = 0; i < 4; ++i) {
    int idx = base + i;
    if (idx < n) row_start[idx] = excl;
    excl += v[i];
  }
  if (blockIdx.x == 0 && t == 0) row_start[n] = total;
}

__global__ void csr_fill(const int* __restrict__ src, const int* __restrict__ dst,
                         int* cursor, int* __restrict__ csr_src) {
  int e = blockIdx.x * blockDim.x + threadIdx.x;
  if (e < NE) {
    int p = atomicAdd(&cursor[dst[e]], 1);
    csr_src[p] = src[e];
  }
}

// ---------------- f32 -> bf16 bulk convert ----------------
__global__ void to_bf16(const float* __restrict__ in, u16* __restrict__ out, int n4) {
  int i = blockIdx.x * 256 + threadIdx.x;
  if (i >= n4) return;
  float4 v = ((const float4*)in)[i];
  uint2 o;
  o.x = pk2(v.x, v.y);
  o.y = pk2(v.z, v.w);
  *(uint2*)(out + (size_t)i * 4) = o;
}

// ---------------- weight pack: W[256][K] f32 -> Wp[ks][c][lane][8] bf16 ----------------
// element (ks,c,l,j) = W[c*16 + (l&15)][ks*32 + (l>>4)*8 + j]
__global__ void pack_w(const float* __restrict__ W, u16* __restrict__ Wp, int K) {
  int id = blockIdx.x * 256 + threadIdx.x;
  if (id >= K * 32) return;  // (K/32) * 16 * 64
  int l = id & 63;
  int c = (id >> 6) & 15;
  int ks = id >> 10;
  int n = c * 16 + (l & 15);
  int k = ks * 32 + (l >> 4) * 8;
  const float* src = W + (size_t)n * K + k;
  uint4 o;
  o.x = pk2(src[0], src[1]);
  o.y = pk2(src[2], src[3]);
  o.z = pk2(src[4], src[5]);
  o.w = pk2(src[6], src[7]);
  *(uint4*)(Wp + (size_t)id * 8) = o;
}

__global__ void add_bias(const float* __restrict__ a, const float* __restrict__ b,
                         float* __restrict__ o) {
  int i = threadIdx.x;
  o[i] = a[i] + b[i];
}

// ---------------- gather-mean (bf16 in/out, f32 accum): one wave per node ----------------
template <int D>
__global__ __launch_bounds__(256) void gather_mean_bf(
    const u16* __restrict__ feat, const int* __restrict__ csr_src,
    const int* __restrict__ row_start, u16* __restrict__ agg, int n) {
  int node = (blockIdx.x * 256 + threadIdx.x) >> 6;
  int lane = threadIdx.x & 63;
  if (node >= n) return;
  int beg = row_start[node], end = row_start[node + 1];
  if (D == 256) {
    float a0 = 0.f, a1 = 0.f, a2 = 0.f, a3 = 0.f;
    for (int e = beg; e < end; ++e) {
      int s = csr_src[e];
      ushort4 u = *(const ushort4*)(feat + (size_t)s * 256 + lane * 4);
      a0 += bf2f(u.x); a1 += bf2f(u.y); a2 += bf2f(u.z); a3 += bf2f(u.w);
    }
    float inv = 1.0f / fmaxf((float)(end - beg), 1.0f);
    uint2 o;
    o.x = pk2(a0 * inv, a1 * inv);
    o.y = pk2(a2 * inv, a3 * inv);
    *(uint2*)(agg + (size_t)node * 256 + lane * 4) = o;
  } else {
    float a0 = 0.f, a1 = 0.f;
    for (int e = beg; e < end; ++e) {
      int s = csr_src[e];
      ushort2 u = *(const ushort2*)(feat + (size_t)s * 128 + lane * 2);
      a0 += bf2f(u.x); a1 += bf2f(u.y);
    }
    float inv = 1.0f / fmaxf((float)(end - beg), 1.0f);
    *(u32*)(agg + (size_t)node * 128 + lane * 2) = pk2(a0 * inv, a1 * inv);
  }
}

// ---------------- fused SAGE update, bf16 MFMA ----------------
// out[i,:] = elu( agg[i,:] @ Wl^T + xdst[i,:] @ Wr^T + bias ),  bf16 in / bf16 out.
// Wp are fragment-packed weights. Per block: 64 rows (4 waves x 16), 256 cols.
// mfma(w_frag, x_frag, acc): lane l, tile c, reg r -> out[row0+16w+(l&15)][c*16+(l>>4)*4+r]
template <int K1, int K2>
__global__ __launch_bounds__(256) void sage_mfma(
    const u16* __restrict__ agg, const u16* xdst,
    const u16* __restrict__ Wp1, const u16* __restrict__ Wp2,
    const float* __restrict__ bias, u16* out, int M) {
  const int t = threadIdx.x;
  const int w = t >> 6;
  const int l = t & 63;
  const int lr = l & 15;
  const int lk = l >> 4;
  const int row = blockIdx.x * 64 + w * 16 + lr;
  const int arow = row < M - 1 ? row : M - 1;

  f32x4 acc[16];
  #pragma unroll
  for (int c = 0; c < 16; ++c) acc[c] = (f32x4){0.f, 0.f, 0.f, 0.f};

  {
    const u16* xp = agg + (size_t)arow * K1 + lk * 8;
    const u16* wp = Wp1 + (size_t)l * 8;
    #pragma unroll 1
    for (int ks = 0; ks < K1 / 32; ++ks) {
      v8s xf = *(const v8s*)(xp + ks * 32);
      #pragma unroll
      for (int c = 0; c < 16; ++c) {
        v8s wf = *(const v8s*)(wp + (size_t)(ks * 16 + c) * 512);
        acc[c] = __builtin_amdgcn_mfma_f32_16x16x32_bf16(wf, xf, acc[c], 0, 0, 0);
      }
    }
  }
  {
    const u16* xp = xdst + (size_t)arow * K2 + lk * 8;
    const u16* wp = Wp2 + (size_t)l * 8;
    #pragma unroll 1
    for (int ks = 0; ks < K2 / 32; ++ks) {
      v8s xf = *(const v8s*)(xp + ks * 32);
      #pragma unroll
      for (int c = 0; c < 16; ++c) {
        v8s wf = *(const v8s*)(wp + (size_t)(ks * 16 + c) * 512);
        acc[c] = __builtin_amdgcn_mfma_f32_16x16x32_bf16(wf, xf, acc[c], 0, 0, 0);
      }
    }
  }

  if (row < M) {
    u16* orow = out + (size_t)row * 256 + lk * 4;
    #pragma unroll
    for (int c = 0; c < 16; ++c) {
      f32x4 bv = *(const f32x4*)(bias + c * 16 + lk * 4);
      float e0 = elu_f(acc[c][0] + bv[0]);
      float e1 = elu_f(acc[c][1] + bv[1]);
      float e2 = elu_f(acc[c][2] + bv[2]);
      float e3 = elu_f(acc[c][3] + bv[3]);
      uint2 o;
      o.x = pk2(e0, e1);
      o.y = pk2(e2, e3);
      *(uint2*)(orow + c * 16) = o;
    }
  }
}

// ---------------- output projection (bf16 author) ----------------
__global__ __launch_bounds__(256) void out_proj(const u16* __restrict__ author,
                                                const float* __restrict__ W,
                                                const float* __restrict__ b,
                                                float* __restrict__ out, int M) {
  __shared__ float ws[10 * 256];
  __shared__ float bs[10];
  int t = threadIdx.x;
  for (int i = t; i < 2560; i += 256) ws[i] = W[i];
  if (t < 10) bs[t] = b[t];
  __syncthreads();
  int wave = t >> 6, lane = t & 63;
  int row = blockIdx.x * 4 + wave;
  if (row >= M) return;
  ushort4 u = *(const ushort4*)(author + (size_t)row * 256 + lane * 4);
  float a0 = bf2f(u.x), a1 = bf2f(u.y), a2 = bf2f(u.z), a3 = bf2f(u.w);
  float p[10];
  #pragma unroll
  for (int n = 0; n < 10; ++n) {
    const float* w = ws + n * 256 + lane * 4;
    p[n] = a0 * w[0] + a1 * w[1] + a2 * w[2] + a3 * w[3];
  }
  #pragma unroll
  for (int off = 32; off > 0; off >>= 1) {
    #pragma unroll
    for (int n = 0; n < 10; ++n) p[n] += __shfl_down(p[n], off);
  }
  if (lane == 0) {
    #pragma unroll
    for (int n = 0; n < 10; ++n) out[(size_t)row * 10 + n] = p[n] + bs[n];
  }
}

extern "C" void kernel_launch(void* const* d_in, const int* in_sizes, int n_in,
                              void* d_out, int out_size, void* d_ws, size_t ws_size,
                              hipStream_t stream) {
  const float* x_author = (const float*)d_in[0];
  const float* x_paper  = (const float*)d_in[1];
  const int* ei_a2p = (const int*)d_in[2];
  const int* ei_p2a = (const int*)d_in[3];
  const int* src_ap = ei_a2p;       // author indices
  const int* dst_ap = ei_a2p + NE;  // paper indices
  const int* src_pa = ei_p2a;       // paper indices
  const int* dst_pa = ei_p2a + NE;  // author indices
  const float* Wl0_ap = (const float*)d_in[4];
  const float* bl0_ap = (const float*)d_in[5];
  const float* Wr0_ap = (const float*)d_in[6];
  const float* br0_ap = (const float*)d_in[7];
  const float* Wl0_pa = (const float*)d_in[8];
  const float* bl0_pa = (const float*)d_in[9];
  const float* Wr0_pa = (const float*)d_in[10];
  const float* br0_pa = (const float*)d_in[11];
  const float* Wl_ap = (const float*)d_in[12];
  const float* bl_ap = (const float*)d_in[13];
  const float* Wr_ap = (const float*)d_in[14];
  const float* br_ap = (const float*)d_in[15];
  const float* Wl_pa = (const float*)d_in[16];
  const float* bl_pa = (const float*)d_in[17];
  const float* Wr_pa = (const float*)d_in[18];
  const float* br_pa = (const float*)d_in[19];
  const float* W_out = (const float*)d_in[20];
  const float* b_out = (const float*)d_in[21];
  float* out = (float*)d_out;

  // ---- workspace layout (byte offsets, 256B-aligned chunks) ----
  char* base = (char*)d_ws;
  size_t o = 0;
  auto alloc = [&](size_t bytes) {
    void* p = base + o;
    o += (bytes + 255) & ~(size_t)255;
    return p;
  };
  u16* paper  = (u16*)alloc((size_t)NP * 256 * 2);
  u16* author = (u16*)alloc((size_t)NA * 256 * 2);
  u16* agg_p  = (u16*)alloc((size_t)NP * 256 * 2);
  u16* agg_a  = (u16*)alloc((size_t)NA * 256 * 2);
  u16* xp_bf  = (u16*)alloc((size_t)NP * 256 * 2);
  u16* xa_bf  = (u16*)alloc((size_t)NA * 128 * 2);
  u16* wp0_ap_l = (u16*)alloc(128 * 256 * 2);
  u16* wp0_ap_r = (u16*)alloc(256 * 256 * 2);
  u16* wp0_pa_l = (u16*)alloc(256 * 256 * 2);
  u16* wp0_pa_r = (u16*)alloc(128 * 256 * 2);
  u16* wp_ap_l = (u16*)alloc(2 * 256 * 256 * 2);
  u16* wp_ap_r = (u16*)alloc(2 * 256 * 256 * 2);
  u16* wp_pa_l = (u16*)alloc(2 * 256 * 256 * 2);
  u16* wp_pa_r = (u16*)alloc(2 * 256 * 256 * 2);
  float* bias0_ap = (float*)alloc(256 * 4);
  float* bias0_pa = (float*)alloc(256 * 4);
  float* bias_ap  = (float*)alloc(2 * 256 * 4);
  float* bias_pa  = (float*)alloc(2 * 256 * 4);
  int* cnt_p  = (int*)alloc((size_t)(NP + NA) * 4);  // cnt_p + cnt_a contiguous
  int* cnt_a  = cnt_p + NP;
  int* rs_p   = (int*)alloc((size_t)(NP + 1) * 4);
  int* rs_a   = (int*)alloc((size_t)(NA + 1) * 4);
  int* cur_p  = (int*)alloc((size_t)NP * 4);
  int* cur_a  = (int*)alloc((size_t)NA * 4);
  int* csrc_p = (int*)alloc((size_t)NE * 4);
  int* csrc_a = (int*)alloc((size_t)NE * 4);
  int* bsum_p = (int*)alloc(128 * 4);
  int* bsum_a = (int*)alloc(128 * 4);

  const int NBP = (NP + SCAN_CHUNK - 1) / SCAN_CHUNK;  // 98
  const int NBA = (NA + SCAN_CHUNK - 1) / SCAN_CHUNK;  // 49

  // ---- CSR build (once, reused by all 3 layers) ----
  hipMemsetAsync(cnt_p, 0, (size_t)(NP + NA) * 4, stream);
  count_deg_i<<<(2 * NE + 255) / 256, 256, 0, stream>>>(dst_ap, dst_pa, cnt_p, cnt_a);
  block_sums_k<<<NBP, 256, 0, stream>>>(cnt_p, bsum_p, NP);
  block_sums_k<<<NBA, 256, 0, stream>>>(cnt_a, bsum_a, NA);
  scan_bsums_k<<<1, 256, 0, stream>>>(bsum_p, NBP);
  scan_bsums_k<<<1, 256, 0, stream>>>(bsum_a, NBA);
  scan_final_k<<<NBP, 256, 0, stream>>>(cnt_p, bsum_p, rs_p, NP, NE);
  scan_final_k<<<NBA, 256, 0, stream>>>(cnt_a, bsum_a, rs_a, NA, NE);
  hipMemcpyAsync(cur_p, rs_p, (size_t)NP * 4, hipMemcpyDeviceToDevice, stream);
  hipMemcpyAsync(cur_a, rs_a, (size_t)NA * 4, hipMemcpyDeviceToDevice, stream);
  csr_fill<<<(NE + 255) / 256, 256, 0, stream>>>(src_ap, dst_ap, cur_p, csrc_p);
  csr_fill<<<(NE + 255) / 256, 256, 0, stream>>>(src_pa, dst_pa, cur_a, csrc_a);

  // ---- input conversion to bf16 ----
  to_bf16<<<((NP * 256 / 4) + 255) / 256, 256, 0, stream>>>(x_paper, xp_bf, NP * 256 / 4);
  to_bf16<<<((NA * 128 / 4) + 255) / 256, 256, 0, stream>>>(x_author, xa_bf, NA * 128 / 4);

  // ---- weight pack (f32 -> bf16 MFMA-fragment order) ----
  pack_w<<<(128 * 32 + 255) / 256, 256, 0, stream>>>(Wl0_ap, wp0_ap_l, 128);
  pack_w<<<(256 * 32 + 255) / 256, 256, 0, stream>>>(Wr0_ap, wp0_ap_r, 256);
  pack_w<<<(256 * 32 + 255) / 256, 256, 0, stream>>>(Wl0_pa, wp0_pa_l, 256);
  pack_w<<<(128 * 32 + 255) / 256, 256, 0, stream>>>(Wr0_pa, wp0_pa_r, 128);
  for (int l = 0; l < 2; ++l) {
    pack_w<<<(256 * 32 + 255) / 256, 256, 0, stream>>>(Wl_ap + (size_t)l * 65536, wp_ap_l + (size_t)l * 65536, 256);
    pack_w<<<(256 * 32 + 255) / 256, 256, 0, stream>>>(Wr_ap + (size_t)l * 65536, wp_ap_r + (size_t)l * 65536, 256);
    pack_w<<<(256 * 32 + 255) / 256, 256, 0, stream>>>(Wl_pa + (size_t)l * 65536, wp_pa_l + (size_t)l * 65536, 256);
    pack_w<<<(256 * 32 + 255) / 256, 256, 0, stream>>>(Wr_pa + (size_t)l * 65536, wp_pa_r + (size_t)l * 65536, 256);
  }
  add_bias<<<1, 256, 0, stream>>>(bl0_ap, br0_ap, bias0_ap);
  add_bias<<<1, 256, 0, stream>>>(bl0_pa, br0_pa, bias0_pa);
  for (int l = 0; l < 2; ++l) {
    add_bias<<<1, 256, 0, stream>>>(bl_ap + l * 256, br_ap + l * 256, bias_ap + l * 256);
    add_bias<<<1, 256, 0, stream>>>(bl_pa + l * 256, br_pa + l * 256, bias_pa + l * 256);
  }

  // ---- layer 0 (author:128, paper:256 inputs) ----
  gather_mean_bf<128><<<(NP * 64 + 255) / 256, 256, 0, stream>>>(xa_bf, csrc_p, rs_p, agg_p, NP);
  gather_mean_bf<256><<<(NA * 64 + 255) / 256, 256, 0, stream>>>(xp_bf, csrc_a, rs_a, agg_a, NA);
  sage_mfma<128, 256><<<(NP + 63) / 64, 256, 0, stream>>>(
      agg_p, xp_bf, wp0_ap_l, wp0_ap_r, bias0_ap, paper, NP);
  sage_mfma<256, 128><<<(NA + 63) / 64, 256, 0, stream>>>(
      agg_a, xa_bf, wp0_pa_l, wp0_pa_r, bias0_pa, author, NA);

  // ---- layers 1..2 (hidden 256; gathers BEFORE in-place updates) ----
  for (int l = 0; l < 2; ++l) {
    gather_mean_bf<256><<<(NP * 64 + 255) / 256, 256, 0, stream>>>(author, csrc_p, rs_p, agg_p, NP);
    gather_mean_bf<256><<<(NA * 64 + 255) / 256, 256, 0, stream>>>(paper, csrc_a, rs_a, agg_a, NA);
    sage_mfma<256, 256><<<(NP + 63) / 64, 256, 0, stream>>>(
        agg_p, paper, wp_ap_l + (size_t)l * 65536, wp_ap_r + (size_t)l * 65536,
        bias_ap + (size_t)l * 256, paper, NP);
    sage_mfma<256, 256><<<(NA + 63) / 64, 256, 0, stream>>>(
        agg_a, author, wp_pa_l + (size_t)l * 65536, wp_pa_r + (size_t)l * 65536,
        bias_pa + (size_t)l * 256, author, NA);
  }

  // ---- output projection ----
  out_proj<<<(NA + 3) / 4, 256, 0, stream>>>(author, W_out, b_out, out, NA);
}

// Round 4
// 720.498 us; speedup vs baseline: 7.5107x; 1.5343x over previous
//
#include <hip/hip_runtime.h>
#include <hip/hip_bf16.h>
#include <cstddef>

#define NA 50000
#define NP 100000
#define NE 200000
#define SCAN_CHUNK 1024

typedef unsigned short u16;
typedef unsigned int u32;
typedef short v8s __attribute__((ext_vector_type(8)));
typedef float f32x4 __attribute__((ext_vector_type(4)));

__device__ __forceinline__ float elu_f(float x) {
  return x > 0.0f ? x : expm1f(x);
}
__device__ __forceinline__ u16 f2bf(float x) {
  u32 u = __float_as_uint(x);
  return (u16)((u + 0x7fffu + ((u >> 16) & 1u)) >> 16);
}
__device__ __forceinline__ float bf2f(u16 h) {
  return __uint_as_float(((u32)h) << 16);
}
__device__ __forceinline__ u32 pk2(float a, float b) {
  return (u32)f2bf(a) | ((u32)f2bf(b) << 16);
}

// ---------------- degree counting (int) ----------------
__global__ void count_deg_i(const int* __restrict__ dst_p, const int* __restrict__ dst_a,
                            int* cnt_p, int* cnt_a) {
  int i = blockIdx.x * blockDim.x + threadIdx.x;
  if (i < NE) atomicAdd(&cnt_p[dst_p[i]], 1);
  else if (i < 2 * NE) atomicAdd(&cnt_a[dst_a[i - NE]], 1);
}

// ---------------- 3-kernel exclusive scan ----------------
__global__ void block_sums_k(const int* __restrict__ cnt, int* __restrict__ bsums, int n) {
  __shared__ int red[256];
  int t = threadIdx.x;
  int base = blockIdx.x * SCAN_CHUNK + t * 4;
  int s = 0;
  #pragma unroll
  for (int i = 0; i < 4; ++i) {
    int idx = base + i;
    if (idx < n) s += cnt[idx];
  }
  red[t] = s;
  __syncthreads();
  for (int off = 128; off > 0; off >>= 1) {
    if (t < off) red[t] += red[t + off];
    __syncthreads();
  }
  if (t == 0) bsums[blockIdx.x] = red[0];
}

__global__ void scan_bsums_k(int* bsums, int nb) {  // nb <= 256, single block
  __shared__ int tmp[256];
  int t = threadIdx.x;
  int orig = (t < nb) ? bsums[t] : 0;
  tmp[t] = orig;
  __syncthreads();
  for (int off = 1; off < 256; off <<= 1) {
    int u = (t >= off) ? tmp[t - off] : 0;
    __syncthreads();
    tmp[t] += u;
    __syncthreads();
  }
  if (t < nb) bsums[t] = tmp[t] - orig;  // exclusive
}

__global__ void scan_final_k(const int* __restrict__ cnt, const int* __restrict__ bsums,
                             int* __restrict__ row_start, int n, int total) {
  __shared__ int red[256];
  int t = threadIdx.x;
  int base = blockIdx.x * SCAN_CHUNK + t * 4;
  int v[4];
  int s = 0;
  #pragma unroll
  for (int i = 0; i < 4; ++i) {
    int idx = base + i;
    v[i] = (idx < n) ? cnt[idx] : 0;
    s += v[i];
  }
  int orig = s;
  red[t] = s;
  __syncthreads();
  for (int off = 1; off < 256; off <<= 1) {
    int u = (t >= off) ? red[t - off] : 0;
    __syncthreads();
    red[t] += u;
    __syncthreads();
  }
  int excl = red[t] - orig + bsums[blockIdx.x];
  #pragma unroll
  for (int i = 0; i < 4; ++i) {
    int idx = base + i;
    if (idx < n) row_start[idx] = excl;
    excl += v[i];
  }
  if (blockIdx.x == 0 && t == 0) row_start[n] = total;
}

__global__ void csr_fill(const int* __restrict__ src, const int* __restrict__ dst,
                         int* cursor, int* __restrict__ csr_src) {
  int e = blockIdx.x * blockDim.x + threadIdx.x;
  if (e < NE) {
    int p = atomicAdd(&cursor[dst[e]], 1);
    csr_src[p] = src[e];
  }
}

// ---------------- f32 -> bf16 bulk convert ----------------
__global__ void to_bf16(const float* __restrict__ in, u16* __restrict__ out, int n4) {
  int i = blockIdx.x * 256 + threadIdx.x;
  if (i >= n4) return;
  float4 v = ((const float4*)in)[i];
  uint2 o;
  o.x = pk2(v.x, v.y);
  o.y = pk2(v.z, v.w);
  *(uint2*)(out + (size_t)i * 4) = o;
}

// ---------------- weight pack: W[256][K] f32 -> Wp[ks][c][lane][8] bf16 ----------------
// element (ks,c,l,j) = W[c*16 + (l&15)][ks*32 + (l>>4)*8 + j]
__global__ void pack_w(const float* __restrict__ W, u16* __restrict__ Wp, int K) {
  int id = blockIdx.x * 256 + threadIdx.x;
  if (id >= K * 32) return;  // (K/32) * 16 * 64
  int l = id & 63;
  int c = (id >> 6) & 15;
  int ks = id >> 10;
  int n = c * 16 + (l & 15);
  int k = ks * 32 + (l >> 4) * 8;
  const float* src = W + (size_t)n * K + k;
  uint4 o;
  o.x = pk2(src[0], src[1]);
  o.y = pk2(src[2], src[3]);
  o.z = pk2(src[4], src[5]);
  o.w = pk2(src[6], src[7]);
  *(uint4*)(Wp + (size_t)id * 8) = o;
}

__global__ void add_bias(const float* __restrict__ a, const float* __restrict__ b,
                         float* __restrict__ o) {
  int i = threadIdx.x;
  o[i] = a[i] + b[i];
}

// ---------------- gather-mean (bf16 in/out, f32 accum): one wave per node ----------------
template <int D>
__global__ __launch_bounds__(256) void gather_mean_bf(
    const u16* __restrict__ feat, const int* __restrict__ csr_src,
    const int* __restrict__ row_start, u16* __restrict__ agg, int n) {
  int node = (blockIdx.x * 256 + threadIdx.x) >> 6;
  int lane = threadIdx.x & 63;
  if (node >= n) return;
  int beg = row_start[node], end = row_start[node + 1];
  if (D == 256) {
    float a0 = 0.f, a1 = 0.f, a2 = 0.f, a3 = 0.f;
    for (int e = beg; e < end; ++e) {
      int s = csr_src[e];
      ushort4 u = *(const ushort4*)(feat + (size_t)s * 256 + lane * 4);
      a0 += bf2f(u.x); a1 += bf2f(u.y); a2 += bf2f(u.z); a3 += bf2f(u.w);
    }
    float inv = 1.0f / fmaxf((float)(end - beg), 1.0f);
    uint2 o;
    o.x = pk2(a0 * inv, a1 * inv);
    o.y = pk2(a2 * inv, a3 * inv);
    *(uint2*)(agg + (size_t)node * 256 + lane * 4) = o;
  } else {
    float a0 = 0.f, a1 = 0.f;
    for (int e = beg; e < end; ++e) {
      int s = csr_src[e];
      ushort2 u = *(const ushort2*)(feat + (size_t)s * 128 + lane * 2);
      a0 += bf2f(u.x); a1 += bf2f(u.y);
    }
    float inv = 1.0f / fmaxf((float)(end - beg), 1.0f);
    *(u32*)(agg + (size_t)node * 128 + lane * 2) = pk2(a0 * inv, a1 * inv);
  }
}

// ---------------- fused SAGE update, bf16 MFMA, LDS-staged weights ----------------
// Block: 512 threads = 8 waves, 32 rows/wave (2 x 16-row tiles) = 256 rows/block.
// Weights staged in 64 KB LDS chunks (half a 256x256 packed matrix per stage),
// shared by all 8 waves; each fragment reused by 2 row-tiles.
template <int K>
__device__ __forceinline__ void sage_phase(
    const u16* __restrict__ A, const u16* __restrict__ Wp,
    f32x4 (&acc)[2][16], u16* lds_w, int ar0, int ar1, int lk, int l, int t) {
  const u16* xp0 = A + (size_t)ar0 * K + lk * 8;
  const u16* xp1 = A + (size_t)ar1 * K + lk * 8;
  #pragma unroll
  for (int kh = 0; kh < K / 128; ++kh) {
    __syncthreads();
    const uint4* src = (const uint4*)(Wp + (size_t)kh * 32768);
    uint4* dst = (uint4*)lds_w;
    #pragma unroll
    for (int i = 0; i < 8; ++i) dst[t + i * 512] = src[t + i * 512];
    __syncthreads();
    #pragma unroll
    for (int ks = 0; ks < 4; ++ks) {
      v8s xf0 = *(const v8s*)(xp0 + (kh * 4 + ks) * 32);
      v8s xf1 = *(const v8s*)(xp1 + (kh * 4 + ks) * 32);
      #pragma unroll
      for (int c = 0; c < 16; ++c) {
        v8s wf = *(const v8s*)(lds_w + (size_t)((ks * 16 + c) * 64 + l) * 8);
        acc[0][c] = __builtin_amdgcn_mfma_f32_16x16x32_bf16(wf, xf0, acc[0][c], 0, 0, 0);
        acc[1][c] = __builtin_amdgcn_mfma_f32_16x16x32_bf16(wf, xf1, acc[1][c], 0, 0, 0);
      }
    }
  }
}

template <int K1, int K2>
__global__ __launch_bounds__(512) void sage_mfma(
    const u16* __restrict__ agg, const u16* xdst,
    const u16* __restrict__ Wp1, const u16* __restrict__ Wp2,
    const float* __restrict__ bias, u16* out, int M) {
  __shared__ __align__(16) u16 lds_w[32768];  // 64 KB
  const int t = threadIdx.x;
  const int w = t >> 6;
  const int l = t & 63;
  const int lr = l & 15;
  const int lk = l >> 4;
  const int row0 = blockIdx.x * 256 + w * 32 + lr;
  const int row1 = row0 + 16;
  const int ar0 = row0 < M - 1 ? row0 : M - 1;
  const int ar1 = row1 < M - 1 ? row1 : M - 1;

  f32x4 acc[2][16];
  #pragma unroll
  for (int rt = 0; rt < 2; ++rt)
    #pragma unroll
    for (int c = 0; c < 16; ++c) acc[rt][c] = (f32x4){0.f, 0.f, 0.f, 0.f};

  sage_phase<K1>(agg, Wp1, acc, lds_w, ar0, ar1, lk, l, t);
  sage_phase<K2>(xdst, Wp2, acc, lds_w, ar0, ar1, lk, l, t);

  // epilogue: bias + ELU + bf16 store
  #pragma unroll
  for (int rt = 0; rt < 2; ++rt) {
    int row = rt == 0 ? row0 : row1;
    if (row < M) {
      u16* orow = out + (size_t)row * 256 + lk * 4;
      #pragma unroll
      for (int c = 0; c < 16; ++c) {
        f32x4 bv = *(const f32x4*)(bias + c * 16 + lk * 4);
        float e0 = elu_f(acc[rt][c][0] + bv[0]);
        float e1 = elu_f(acc[rt][c][1] + bv[1]);
        float e2 = elu_f(acc[rt][c][2] + bv[2]);
        float e3 = elu_f(acc[rt][c][3] + bv[3]);
        uint2 o;
        o.x = pk2(e0, e1);
        o.y = pk2(e2, e3);
        *(uint2*)(orow + c * 16) = o;
      }
    }
  }
}

// ---------------- output projection (bf16 author) ----------------
__global__ __launch_bounds__(256) void out_proj(const u16* __restrict__ author,
                                                const float* __restrict__ W,
                                                const float* __restrict__ b,
                                                float* __restrict__ out, int M) {
  __shared__ float ws[10 * 256];
  __shared__ float bs[10];
  int t = threadIdx.x;
  for (int i = t; i < 2560; i += 256) ws[i] = W[i];
  if (t < 10) bs[t] = b[t];
  __syncthreads();
  int wave = t >> 6, lane = t & 63;
  int row = blockIdx.x * 4 + wave;
  if (row >= M) return;
  ushort4 u = *(const ushort4*)(author + (size_t)row * 256 + lane * 4);
  float a0 = bf2f(u.x), a1 = bf2f(u.y), a2 = bf2f(u.z), a3 = bf2f(u.w);
  float p[10];
  #pragma unroll
  for (int n = 0; n < 10; ++n) {
    const float* w = ws + n * 256 + lane * 4;
    p[n] = a0 * w[0] + a1 * w[1] + a2 * w[2] + a3 * w[3];
  }
  #pragma unroll
  for (int off = 32; off > 0; off >>= 1) {
    #pragma unroll
    for (int n = 0; n < 10; ++n) p[n] += __shfl_down(p[n], off);
  }
  if (lane == 0) {
    #pragma unroll
    for (int n = 0; n < 10; ++n) out[(size_t)row * 10 + n] = p[n] + bs[n];
  }
}

extern "C" void kernel_launch(void* const* d_in, const int* in_sizes, int n_in,
                              void* d_out, int out_size, void* d_ws, size_t ws_size,
                              hipStream_t stream) {
  const float* x_author = (const float*)d_in[0];
  const float* x_paper  = (const float*)d_in[1];
  const int* ei_a2p = (const int*)d_in[2];
  const int* ei_p2a = (const int*)d_in[3];
  const int* src_ap = ei_a2p;       // author indices
  const int* dst_ap = ei_a2p + NE;  // paper indices
  const int* src_pa = ei_p2a;       // paper indices
  const int* dst_pa = ei_p2a + NE;  // author indices
  const float* Wl0_ap = (const float*)d_in[4];
  const float* bl0_ap = (const float*)d_in[5];
  const float* Wr0_ap = (const float*)d_in[6];
  const float* br0_ap = (const float*)d_in[7];
  const float* Wl0_pa = (const float*)d_in[8];
  const float* bl0_pa = (const float*)d_in[9];
  const float* Wr0_pa = (const float*)d_in[10];
  const float* br0_pa = (const float*)d_in[11];
  const float* Wl_ap = (const float*)d_in[12];
  const float* bl_ap = (const float*)d_in[13];
  const float* Wr_ap = (const float*)d_in[14];
  const float* br_ap = (const float*)d_in[15];
  const float* Wl_pa = (const float*)d_in[16];
  const float* bl_pa = (const float*)d_in[17];
  const float* Wr_pa = (const float*)d_in[18];
  const float* br_pa = (const float*)d_in[19];
  const float* W_out = (const float*)d_in[20];
  const float* b_out = (const float*)d_in[21];
  float* out = (float*)d_out;

  // ---- workspace layout (byte offsets, 256B-aligned chunks) ----
  char* base = (char*)d_ws;
  size_t o = 0;
  auto alloc = [&](size_t bytes) {
    void* p = base + o;
    o += (bytes + 255) & ~(size_t)255;
    return p;
  };
  u16* paper  = (u16*)alloc((size_t)NP * 256 * 2);
  u16* author = (u16*)alloc((size_t)NA * 256 * 2);
  u16* agg_p  = (u16*)alloc((size_t)NP * 256 * 2);
  u16* agg_a  = (u16*)alloc((size_t)NA * 256 * 2);
  u16* xp_bf  = (u16*)alloc((size_t)NP * 256 * 2);
  u16* xa_bf  = (u16*)alloc((size_t)NA * 128 * 2);
  u16* wp0_ap_l = (u16*)alloc(128 * 256 * 2);
  u16* wp0_ap_r = (u16*)alloc(256 * 256 * 2);
  u16* wp0_pa_l = (u16*)alloc(256 * 256 * 2);
  u16* wp0_pa_r = (u16*)alloc(128 * 256 * 2);
  u16* wp_ap_l = (u16*)alloc(2 * 256 * 256 * 2);
  u16* wp_ap_r = (u16*)alloc(2 * 256 * 256 * 2);
  u16* wp_pa_l = (u16*)alloc(2 * 256 * 256 * 2);
  u16* wp_pa_r = (u16*)alloc(2 * 256 * 256 * 2);
  float* bias0_ap = (float*)alloc(256 * 4);
  float* bias0_pa = (float*)alloc(256 * 4);
  float* bias_ap  = (float*)alloc(2 * 256 * 4);
  float* bias_pa  = (float*)alloc(2 * 256 * 4);
  int* cnt_p  = (int*)alloc((size_t)(NP + NA) * 4);  // cnt_p + cnt_a contiguous
  int* cnt_a  = cnt_p + NP;
  int* rs_p   = (int*)alloc((size_t)(NP + 1) * 4);
  int* rs_a   = (int*)alloc((size_t)(NA + 1) * 4);
  int* cur_p  = (int*)alloc((size_t)NP * 4);
  int* cur_a  = (int*)alloc((size_t)NA * 4);
  int* csrc_p = (int*)alloc((size_t)NE * 4);
  int* csrc_a = (int*)alloc((size_t)NE * 4);
  int* bsum_p = (int*)alloc(128 * 4);
  int* bsum_a = (int*)alloc(128 * 4);

  const int NBP = (NP + SCAN_CHUNK - 1) / SCAN_CHUNK;  // 98
  const int NBA = (NA + SCAN_CHUNK - 1) / SCAN_CHUNK;  // 49

  // ---- CSR build (once, reused by all 3 layers) ----
  hipMemsetAsync(cnt_p, 0, (size_t)(NP + NA) * 4, stream);
  count_deg_i<<<(2 * NE + 255) / 256, 256, 0, stream>>>(dst_ap, dst_pa, cnt_p, cnt_a);
  block_sums_k<<<NBP, 256, 0, stream>>>(cnt_p, bsum_p, NP);
  block_sums_k<<<NBA, 256, 0, stream>>>(cnt_a, bsum_a, NA);
  scan_bsums_k<<<1, 256, 0, stream>>>(bsum_p, NBP);
  scan_bsums_k<<<1, 256, 0, stream>>>(bsum_a, NBA);
  scan_final_k<<<NBP, 256, 0, stream>>>(cnt_p, bsum_p, rs_p, NP, NE);
  scan_final_k<<<NBA, 256, 0, stream>>>(cnt_a, bsum_a, rs_a, NA, NE);
  hipMemcpyAsync(cur_p, rs_p, (size_t)NP * 4, hipMemcpyDeviceToDevice, stream);
  hipMemcpyAsync(cur_a, rs_a, (size_t)NA * 4, hipMemcpyDeviceToDevice, stream);
  csr_fill<<<(NE + 255) / 256, 256, 0, stream>>>(src_ap, dst_ap, cur_p, csrc_p);
  csr_fill<<<(NE + 255) / 256, 256, 0, stream>>>(src_pa, dst_pa, cur_a, csrc_a);

  // ---- input conversion to bf16 ----
  to_bf16<<<((NP * 256 / 4) + 255) / 256, 256, 0, stream>>>(x_paper, xp_bf, NP * 256 / 4);
  to_bf16<<<((NA * 128 / 4) + 255) / 256, 256, 0, stream>>>(x_author, xa_bf, NA * 128 / 4);

  // ---- weight pack (f32 -> bf16 MFMA-fragment order) ----
  pack_w<<<(128 * 32 + 255) / 256, 256, 0, stream>>>(Wl0_ap, wp0_ap_l, 128);
  pack_w<<<(256 * 32 + 255) / 256, 256, 0, stream>>>(Wr0_ap, wp0_ap_r, 256);
  pack_w<<<(256 * 32 + 255) / 256, 256, 0, stream>>>(Wl0_pa, wp0_pa_l, 256);
  pack_w<<<(128 * 32 + 255) / 256, 256, 0, stream>>>(Wr0_pa, wp0_pa_r, 128);
  for (int l = 0; l < 2; ++l) {
    pack_w<<<(256 * 32 + 255) / 256, 256, 0, stream>>>(Wl_ap + (size_t)l * 65536, wp_ap_l + (size_t)l * 65536, 256);
    pack_w<<<(256 * 32 + 255) / 256, 256, 0, stream>>>(Wr_ap + (size_t)l * 65536, wp_ap_r + (size_t)l * 65536, 256);
    pack_w<<<(256 * 32 + 255) / 256, 256, 0, stream>>>(Wl_pa + (size_t)l * 65536, wp_pa_l + (size_t)l * 65536, 256);
    pack_w<<<(256 * 32 + 255) / 256, 256, 0, stream>>>(Wr_pa + (size_t)l * 65536, wp_pa_r + (size_t)l * 65536, 256);
  }
  add_bias<<<1, 256, 0, stream>>>(bl0_ap, br0_ap, bias0_ap);
  add_bias<<<1, 256, 0, stream>>>(bl0_pa, br0_pa, bias0_pa);
  for (int l = 0; l < 2; ++l) {
    add_bias<<<1, 256, 0, stream>>>(bl_ap + l * 256, br_ap + l * 256, bias_ap + l * 256);
    add_bias<<<1, 256, 0, stream>>>(bl_pa + l * 256, br_pa + l * 256, bias_pa + l * 256);
  }

  // ---- layer 0 (author:128, paper:256 inputs) ----
  gather_mean_bf<128><<<(NP * 64 + 255) / 256, 256, 0, stream>>>(xa_bf, csrc_p, rs_p, agg_p, NP);
  gather_mean_bf<256><<<(NA * 64 + 255) / 256, 256, 0, stream>>>(xp_bf, csrc_a, rs_a, agg_a, NA);
  sage_mfma<128, 256><<<(NP + 255) / 256, 512, 0, stream>>>(
      agg_p, xp_bf, wp0_ap_l, wp0_ap_r, bias0_ap, paper, NP);
  sage_mfma<256, 128><<<(NA + 255) / 256, 512, 0, stream>>>(
      agg_a, xa_bf, wp0_pa_l, wp0_pa_r, bias0_pa, author, NA);

  // ---- layers 1..2 (hidden 256; gathers BEFORE in-place updates) ----
  for (int l = 0; l < 2; ++l) {
    gather_mean_bf<256><<<(NP * 64 + 255) / 256, 256, 0, stream>>>(author, csrc_p, rs_p, agg_p, NP);
    gather_mean_bf<256><<<(NA * 64 + 255) / 256, 256, 0, stream>>>(paper, csrc_a, rs_a, agg_a, NA);
    sage_mfma<256, 256><<<(NP + 255) / 256, 512, 0, stream>>>(
        agg_p, paper, wp_ap_l + (size_t)l * 65536, wp_ap_r + (size_t)l * 65536,
        bias_ap + (size_t)l * 256, paper, NP);
    sage_mfma<256, 256><<<(NA + 255) / 256, 512, 0, stream>>>(
        agg_a, author, wp_pa_l + (size_t)l * 65536, wp_pa_r + (size_t)l * 65536,
        bias_pa + (size_t)l * 256, author, NA);
  }

  // ---- output projection ----
  out_proj<<<(NA + 3) / 4, 256, 0, stream>>>(author, W_out, b_out, out, NA);
}

// Round 5
// 719.423 us; speedup vs baseline: 7.5220x; 1.0015x over previous
//
#include <hip/hip_runtime.h>
#include <hip/hip_bf16.h>
#include <cstddef>

#define NA 50000
#define NP 100000
#define NE 200000
#define SCAN_CHUNK 1024

typedef unsigned short u16;
typedef unsigned int u32;
typedef short v8s __attribute__((ext_vector_type(8)));
typedef float f32x4 __attribute__((ext_vector_type(4)));

__device__ __forceinline__ float elu_f(float x) {
  return x > 0.0f ? x : expm1f(x);
}
__device__ __forceinline__ u16 f2bf(float x) {
  u32 u = __float_as_uint(x);
  return (u16)((u + 0x7fffu + ((u >> 16) & 1u)) >> 16);
}
__device__ __forceinline__ float bf2f(u16 h) {
  return __uint_as_float(((u32)h) << 16);
}
__device__ __forceinline__ u32 pk2(float a, float b) {
  return (u32)f2bf(a) | ((u32)f2bf(b) << 16);
}

// ---------------- degree counting (int) ----------------
__global__ void count_deg_i(const int* __restrict__ dst_p, const int* __restrict__ dst_a,
                            int* cnt_p, int* cnt_a) {
  int i = blockIdx.x * blockDim.x + threadIdx.x;
  if (i < NE) atomicAdd(&cnt_p[dst_p[i]], 1);
  else if (i < 2 * NE) atomicAdd(&cnt_a[dst_a[i - NE]], 1);
}

// ---------------- 3-kernel exclusive scan ----------------
__global__ void block_sums_k(const int* __restrict__ cnt, int* __restrict__ bsums, int n) {
  __shared__ int red[256];
  int t = threadIdx.x;
  int base = blockIdx.x * SCAN_CHUNK + t * 4;
  int s = 0;
  #pragma unroll
  for (int i = 0; i < 4; ++i) {
    int idx = base + i;
    if (idx < n) s += cnt[idx];
  }
  red[t] = s;
  __syncthreads();
  for (int off = 128; off > 0; off >>= 1) {
    if (t < off) red[t] += red[t + off];
    __syncthreads();
  }
  if (t == 0) bsums[blockIdx.x] = red[0];
}

__global__ void scan_bsums_k(int* bsums, int nb) {  // nb <= 256, single block
  __shared__ int tmp[256];
  int t = threadIdx.x;
  int orig = (t < nb) ? bsums[t] : 0;
  tmp[t] = orig;
  __syncthreads();
  for (int off = 1; off < 256; off <<= 1) {
    int u = (t >= off) ? tmp[t - off] : 0;
    __syncthreads();
    tmp[t] += u;
    __syncthreads();
  }
  if (t < nb) bsums[t] = tmp[t] - orig;  // exclusive
}

__global__ void scan_final_k(const int* __restrict__ cnt, const int* __restrict__ bsums,
                             int* __restrict__ row_start, int n, int total) {
  __shared__ int red[256];
  int t = threadIdx.x;
  int base = blockIdx.x * SCAN_CHUNK + t * 4;
  int v[4];
  int s = 0;
  #pragma unroll
  for (int i = 0; i < 4; ++i) {
    int idx = base + i;
    v[i] = (idx < n) ? cnt[idx] : 0;
    s += v[i];
  }
  int orig = s;
  red[t] = s;
  __syncthreads();
  for (int off = 1; off < 256; off <<= 1) {
    int u = (t >= off) ? red[t - off] : 0;
    __syncthreads();
    red[t] += u;
    __syncthreads();
  }
  int excl = red[t] - orig + bsums[blockIdx.x];
  #pragma unroll
  for (int i = 0; i < 4; ++i) {
    int idx = base + i;
    if (idx < n) row_start[idx] = excl;
    excl += v[i];
  }
  if (blockIdx.x == 0 && t == 0) row_start[n] = total;
}

__global__ void csr_fill(const int* __restrict__ src, const int* __restrict__ dst,
                         int* cursor, int* __restrict__ csr_src) {
  int e = blockIdx.x * blockDim.x + threadIdx.x;
  if (e < NE) {
    int p = atomicAdd(&cursor[dst[e]], 1);
    csr_src[p] = src[e];
  }
}

// ---------------- f32 -> bf16 bulk convert ----------------
__global__ void to_bf16(const float* __restrict__ in, u16* __restrict__ out, int n4) {
  int i = blockIdx.x * 256 + threadIdx.x;
  if (i >= n4) return;
  float4 v = ((const float4*)in)[i];
  uint2 o;
  o.x = pk2(v.x, v.y);
  o.y = pk2(v.z, v.w);
  *(uint2*)(out + (size_t)i * 4) = o;
}

// ---------------- weight pack: W[256][K] f32 -> Wp[ks][c][lane][8] bf16 ----------------
// element (ks,c,l,j) = W[c*16 + (l&15)][ks*32 + (l>>4)*8 + j]
__global__ void pack_w(const float* __restrict__ W, u16* __restrict__ Wp, int K) {
  int id = blockIdx.x * 256 + threadIdx.x;
  if (id >= K * 32) return;  // (K/32) * 16 * 64
  int l = id & 63;
  int c = (id >> 6) & 15;
  int ks = id >> 10;
  int n = c * 16 + (l & 15);
  int k = ks * 32 + (l >> 4) * 8;
  const float* src = W + (size_t)n * K + k;
  uint4 o;
  o.x = pk2(src[0], src[1]);
  o.y = pk2(src[2], src[3]);
  o.z = pk2(src[4], src[5]);
  o.w = pk2(src[6], src[7]);
  *(uint4*)(Wp + (size_t)id * 8) = o;
}

__global__ void add_bias(const float* __restrict__ a, const float* __restrict__ b,
                         float* __restrict__ o) {
  int i = threadIdx.x;
  o[i] = a[i] + b[i];
}

// ---------------- gather-mean (bf16 in/out, f32 accum): one wave per node ----------------
template <int D>
__global__ __launch_bounds__(256) void gather_mean_bf(
    const u16* __restrict__ feat, const int* __restrict__ csr_src,
    const int* __restrict__ row_start, u16* __restrict__ agg, int n) {
  int node = (blockIdx.x * 256 + threadIdx.x) >> 6;
  int lane = threadIdx.x & 63;
  if (node >= n) return;
  int beg = row_start[node], end = row_start[node + 1];
  if (D == 256) {
    float a0 = 0.f, a1 = 0.f, a2 = 0.f, a3 = 0.f;
    for (int e = beg; e < end; ++e) {
      int s = csr_src[e];
      ushort4 u = *(const ushort4*)(feat + (size_t)s * 256 + lane * 4);
      a0 += bf2f(u.x); a1 += bf2f(u.y); a2 += bf2f(u.z); a3 += bf2f(u.w);
    }
    float inv = 1.0f / fmaxf((float)(end - beg), 1.0f);
    uint2 o;
    o.x = pk2(a0 * inv, a1 * inv);
    o.y = pk2(a2 * inv, a3 * inv);
    *(uint2*)(agg + (size_t)node * 256 + lane * 4) = o;
  } else {
    float a0 = 0.f, a1 = 0.f;
    for (int e = beg; e < end; ++e) {
      int s = csr_src[e];
      ushort2 u = *(const ushort2*)(feat + (size_t)s * 128 + lane * 2);
      a0 += bf2f(u.x); a1 += bf2f(u.y);
    }
    float inv = 1.0f / fmaxf((float)(end - beg), 1.0f);
    *(u32*)(agg + (size_t)node * 128 + lane * 2) = pk2(a0 * inv, a1 * inv);
  }
}

// ---------------- fused SAGE update, bf16 MFMA, LDS-staged weights ----------------
// Block: 512 threads = 8 waves, 32 rows/wave (2 x 16-row tiles) = 256 rows/block.
// Weights staged in 64 KB LDS chunks (half a 256x256 packed matrix per stage),
// shared by all 8 waves; each fragment reused by 2 row-tiles.
template <int K>
__device__ __forceinline__ void sage_phase(
    const u16* __restrict__ A, const u16* __restrict__ Wp,
    f32x4 (&acc)[2][16], u16* lds_w, int ar0, int ar1, int lk, int l, int t) {
  const u16* xp0 = A + (size_t)ar0 * K + lk * 8;
  const u16* xp1 = A + (size_t)ar1 * K + lk * 8;
  #pragma unroll
  for (int kh = 0; kh < K / 128; ++kh) {
    __syncthreads();
    const uint4* src = (const uint4*)(Wp + (size_t)kh * 32768);
    uint4* dst = (uint4*)lds_w;
    #pragma unroll
    for (int i = 0; i < 8; ++i) dst[t + i * 512] = src[t + i * 512];
    __syncthreads();
    #pragma unroll
    for (int ks = 0; ks < 4; ++ks) {
      v8s xf0 = *(const v8s*)(xp0 + (kh * 4 + ks) * 32);
      v8s xf1 = *(const v8s*)(xp1 + (kh * 4 + ks) * 32);
      #pragma unroll
      for (int c = 0; c < 16; ++c) {
        v8s wf = *(const v8s*)(lds_w + (size_t)((ks * 16 + c) * 64 + l) * 8);
        acc[0][c] = __builtin_amdgcn_mfma_f32_16x16x32_bf16(wf, xf0, acc[0][c], 0, 0, 0);
        acc[1][c] = __builtin_amdgcn_mfma_f32_16x16x32_bf16(wf, xf1, acc[1][c], 0, 0, 0);
      }
    }
  }
}

template <int K1, int K2>
__global__ __launch_bounds__(512) void sage_mfma(
    const u16* __restrict__ agg, const u16* xdst,
    const u16* __restrict__ Wp1, const u16* __restrict__ Wp2,
    const float* __restrict__ bias, u16* out, int M) {
  __shared__ __align__(16) u16 lds_w[32768];  // 64 KB
  const int t = threadIdx.x;
  const int w = t >> 6;
  const int l = t & 63;
  const int lr = l & 15;
  const int lk = l >> 4;
  const int row0 = blockIdx.x * 256 + w * 32 + lr;
  const int row1 = row0 + 16;
  const int ar0 = row0 < M - 1 ? row0 : M - 1;
  const int ar1 = row1 < M - 1 ? row1 : M - 1;

  f32x4 acc[2][16];
  #pragma unroll
  for (int rt = 0; rt < 2; ++rt)
    #pragma unroll
    for (int c = 0; c < 16; ++c) acc[rt][c] = (f32x4){0.f, 0.f, 0.f, 0.f};

  sage_phase<K1>(agg, Wp1, acc, lds_w, ar0, ar1, lk, l, t);
  sage_phase<K2>(xdst, Wp2, acc, lds_w, ar0, ar1, lk, l, t);

  // epilogue: bias + ELU + bf16 store
  #pragma unroll
  for (int rt = 0; rt < 2; ++rt) {
    int row = rt == 0 ? row0 : row1;
    if (row < M) {
      u16* orow = out + (size_t)row * 256 + lk * 4;
      #pragma unroll
      for (int c = 0; c < 16; ++c) {
        f32x4 bv = *(const f32x4*)(bias + c * 16 + lk * 4);
        float e0 = elu_f(acc[rt][c][0] + bv[0]);
        float e1 = elu_f(acc[rt][c][1] + bv[1]);
        float e2 = elu_f(acc[rt][c][2] + bv[2]);
        float e3 = elu_f(acc[rt][c][3] + bv[3]);
        uint2 o;
        o.x = pk2(e0, e1);
        o.y = pk2(e2, e3);
        *(uint2*)(orow + c * 16) = o;
      }
    }
  }
}

// ---------------- output projection (bf16 author) ----------------
__global__ __launch_bounds__(256) void out_proj(const u16* __restrict__ author,
                                                const float* __restrict__ W,
                                                const float* __restrict__ b,
                                                float* __restrict__ out, int M) {
  __shared__ float ws[10 * 256];
  __shared__ float bs[10];
  int t = threadIdx.x;
  for (int i = t; i < 2560; i += 256) ws[i] = W[i];
  if (t < 10) bs[t] = b[t];
  __syncthreads();
  int wave = t >> 6, lane = t & 63;
  int row = blockIdx.x * 4 + wave;
  if (row >= M) return;
  ushort4 u = *(const ushort4*)(author + (size_t)row * 256 + lane * 4);
  float a0 = bf2f(u.x), a1 = bf2f(u.y), a2 = bf2f(u.z), a3 = bf2f(u.w);
  float p[10];
  #pragma unroll
  for (int n = 0; n < 10; ++n) {
    const float* w = ws + n * 256 + lane * 4;
    p[n] = a0 * w[0] + a1 * w[1] + a2 * w[2] + a3 * w[3];
  }
  #pragma unroll
  for (int off = 32; off > 0; off >>= 1) {
    #pragma unroll
    for (int n = 0; n < 10; ++n) p[n] += __shfl_down(p[n], off);
  }
  if (lane == 0) {
    #pragma unroll
    for (int n = 0; n < 10; ++n) out[(size_t)row * 10 + n] = p[n] + bs[n];
  }
}

extern "C" void kernel_launch(void* const* d_in, const int* in_sizes, int n_in,
                              void* d_out, int out_size, void* d_ws, size_t ws_size,
                              hipStream_t stream) {
  const float* x_author = (const float*)d_in[0];
  const float* x_paper  = (const float*)d_in[1];
  const int* ei_a2p = (const int*)d_in[2];
  const int* ei_p2a = (const int*)d_in[3];
  const int* src_ap = ei_a2p;       // author indices
  const int* dst_ap = ei_a2p + NE;  // paper indices
  const int* src_pa = ei_p2a;       // paper indices
  const int* dst_pa = ei_p2a + NE;  // author indices
  const float* Wl0_ap = (const float*)d_in[4];
  const float* bl0_ap = (const float*)d_in[5];
  const float* Wr0_ap = (const float*)d_in[6];
  const float* br0_ap = (const float*)d_in[7];
  const float* Wl0_pa = (const float*)d_in[8];
  const float* bl0_pa = (const float*)d_in[9];
  const float* Wr0_pa = (const float*)d_in[10];
  const float* br0_pa = (const float*)d_in[11];
  const float* Wl_ap = (const float*)d_in[12];
  const float* bl_ap = (const float*)d_in[13];
  const float* Wr_ap = (const float*)d_in[14];
  const float* br_ap = (const float*)d_in[15];
  const float* Wl_pa = (const float*)d_in[16];
  const float* bl_pa = (const float*)d_in[17];
  const float* Wr_pa = (const float*)d_in[18];
  const float* br_pa = (const float*)d_in[19];
  const float* W_out = (const float*)d_in[20];
  const float* b_out = (const float*)d_in[21];
  float* out = (float*)d_out;

  // ---- workspace layout (byte offsets, 256B-aligned chunks) ----
  char* base = (char*)d_ws;
  size_t o = 0;
  auto alloc = [&](size_t bytes) {
    void* p = base + o;
    o += (bytes + 255) & ~(size_t)255;
    return p;
  };
  u16* paper  = (u16*)alloc((size_t)NP * 256 * 2);
  u16* author = (u16*)alloc((size_t)NA * 256 * 2);
  u16* agg_p  = (u16*)alloc((size_t)NP * 256 * 2);
  u16* agg_a  = (u16*)alloc((size_t)NA * 256 * 2);
  u16* xp_bf  = (u16*)alloc((size_t)NP * 256 * 2);
  u16* xa_bf  = (u16*)alloc((size_t)NA * 128 * 2);
  u16* wp0_ap_l = (u16*)alloc(128 * 256 * 2);
  u16* wp0_ap_r = (u16*)alloc(256 * 256 * 2);
  u16* wp0_pa_l = (u16*)alloc(256 * 256 * 2);
  u16* wp0_pa_r = (u16*)alloc(128 * 256 * 2);
  u16* wp_ap_l = (u16*)alloc(2 * 256 * 256 * 2);
  u16* wp_ap_r = (u16*)alloc(2 * 256 * 256 * 2);
  u16* wp_pa_l = (u16*)alloc(2 * 256 * 256 * 2);
  u16* wp_pa_r = (u16*)alloc(2 * 256 * 256 * 2);
  float* bias0_ap = (float*)alloc(256 * 4);
  float* bias0_pa = (float*)alloc(256 * 4);
  float* bias_ap  = (float*)alloc(2 * 256 * 4);
  float* bias_pa  = (float*)alloc(2 * 256 * 4);
  int* cnt_p  = (int*)alloc((size_t)(NP + NA) * 4);  // cnt_p + cnt_a contiguous
  int* cnt_a  = cnt_p + NP;
  int* rs_p   = (int*)alloc((size_t)(NP + 1) * 4);
  int* rs_a   = (int*)alloc((size_t)(NA + 1) * 4);
  int* cur_p  = (int*)alloc((size_t)NP * 4);
  int* cur_a  = (int*)alloc((size_t)NA * 4);
  int* csrc_p = (int*)alloc((size_t)NE * 4);
  int* csrc_a = (int*)alloc((size_t)NE * 4);
  int* bsum_p = (int*)alloc(128 * 4);
  int* bsum_a = (int*)alloc(128 * 4);

  const int NBP = (NP + SCAN_CHUNK - 1) / SCAN_CHUNK;  // 98
  const int NBA = (NA + SCAN_CHUNK - 1) / SCAN_CHUNK;  // 49

  // ---- CSR build (once, reused by all 3 layers) ----
  hipMemsetAsync(cnt_p, 0, (size_t)(NP + NA) * 4, stream);
  count_deg_i<<<(2 * NE + 255) / 256, 256, 0, stream>>>(dst_ap, dst_pa, cnt_p, cnt_a);
  block_sums_k<<<NBP, 256, 0, stream>>>(cnt_p, bsum_p, NP);
  block_sums_k<<<NBA, 256, 0, stream>>>(cnt_a, bsum_a, NA);
  scan_bsums_k<<<1, 256, 0, stream>>>(bsum_p, NBP);
  scan_bsums_k<<<1, 256, 0, stream>>>(bsum_a, NBA);
  scan_final_k<<<NBP, 256, 0, stream>>>(cnt_p, bsum_p, rs_p, NP, NE);
  scan_final_k<<<NBA, 256, 0, stream>>>(cnt_a, bsum_a, rs_a, NA, NE);
  hipMemcpyAsync(cur_p, rs_p, (size_t)NP * 4, hipMemcpyDeviceToDevice, stream);
  hipMemcpyAsync(cur_a, rs_a, (size_t)NA * 4, hipMemcpyDeviceToDevice, stream);
  csr_fill<<<(NE + 255) / 256, 256, 0, stream>>>(src_ap, dst_ap, cur_p, csrc_p);
  csr_fill<<<(NE + 255) / 256, 256, 0, stream>>>(src_pa, dst_pa, cur_a, csrc_a);

  // ---- input conversion to bf16 ----
  to_bf16<<<((NP * 256 / 4) + 255) / 256, 256, 0, stream>>>(x_paper, xp_bf, NP * 256 / 4);
  to_bf16<<<((NA * 128 / 4) + 255) / 256, 256, 0, stream>>>(x_author, xa_bf, NA * 128 / 4);

  // ---- weight pack (f32 -> bf16 MFMA-fragment order) ----
  pack_w<<<(128 * 32 + 255) / 256, 256, 0, stream>>>(Wl0_ap, wp0_ap_l, 128);
  pack_w<<<(256 * 32 + 255) / 256, 256, 0, stream>>>(Wr0_ap, wp0_ap_r, 256);
  pack_w<<<(256 * 32 + 255) / 256, 256, 0, stream>>>(Wl0_pa, wp0_pa_l, 256);
  pack_w<<<(128 * 32 + 255) / 256, 256, 0, stream>>>(Wr0_pa, wp0_pa_r, 128);
  for (int l = 0; l < 2; ++l) {
    pack_w<<<(256 * 32 + 255) / 256, 256, 0, stream>>>(Wl_ap + (size_t)l * 65536, wp_ap_l + (size_t)l * 65536, 256);
    pack_w<<<(256 * 32 + 255) / 256, 256, 0, stream>>>(Wr_ap + (size_t)l * 65536, wp_ap_r + (size_t)l * 65536, 256);
    pack_w<<<(256 * 32 + 255) / 256, 256, 0, stream>>>(Wl_pa + (size_t)l * 65536, wp_pa_l + (size_t)l * 65536, 256);
    pack_w<<<(256 * 32 + 255) / 256, 256, 0, stream>>>(Wr_pa + (size_t)l * 65536, wp_pa_r + (size_t)l * 65536, 256);
  }
  add_bias<<<1, 256, 0, stream>>>(bl0_ap, br0_ap, bias0_ap);
  add_bias<<<1, 256, 0, stream>>>(bl0_pa, br0_pa, bias0_pa);
  for (int l = 0; l < 2; ++l) {
    add_bias<<<1, 256, 0, stream>>>(bl_ap + l * 256, br_ap + l * 256, bias_ap + l * 256);
    add_bias<<<1, 256, 0, stream>>>(bl_pa + l * 256, br_pa + l * 256, bias_pa + l * 256);
  }

  // ---- layer 0 (author:128, paper:256 inputs) ----
  gather_mean_bf<128><<<(NP * 64 + 255) / 256, 256, 0, stream>>>(xa_bf, csrc_p, rs_p, agg_p, NP);
  gather_mean_bf<256><<<(NA * 64 + 255) / 256, 256, 0, stream>>>(xp_bf, csrc_a, rs_a, agg_a, NA);
  sage_mfma<128, 256><<<(NP + 255) / 256, 512, 0, stream>>>(
      agg_p, xp_bf, wp0_ap_l, wp0_ap_r, bias0_ap, paper, NP);
  sage_mfma<256, 128><<<(NA + 255) / 256, 512, 0, stream>>>(
      agg_a, xa_bf, wp0_pa_l, wp0_pa_r, bias0_pa, author, NA);

  // ---- layers 1..2 (hidden 256; gathers BEFORE in-place updates) ----
  for (int l = 0; l < 2; ++l) {
    gather_mean_bf<256><<<(NP * 64 + 255) / 256, 256, 0, stream>>>(author, csrc_p, rs_p, agg_p, NP);
    gather_mean_bf<256><<<(NA * 64 + 255) / 256, 256, 0, stream>>>(paper, csrc_a, rs_a, agg_a, NA);
    sage_mfma<256, 256><<<(NP + 255) / 256, 512, 0, stream>>>(
        agg_p, paper, wp_ap_l + (size_t)l * 65536, wp_ap_r + (size_t)l * 65536,
        bias_ap + (size_t)l * 256, paper, NP);
    sage_mfma<256, 256><<<(NA + 255) / 256, 512, 0, stream>>>(
        agg_a, author, wp_pa_l + (size_t)l * 65536, wp_pa_r + (size_t)l * 65536,
        bias_pa + (size_t)l * 256, author, NA);
  }

  // ---- output projection ----
  out_proj<<<(NA + 3) / 4, 256, 0, stream>>>(author, W_out, b_out, out, NA);
}

// Round 6
// 676.915 us; speedup vs baseline: 7.9943x; 1.0628x over previous
//
#include <hip/hip_runtime.h>
#include <hip/hip_bf16.h>
#include <cstddef>

#define NA 50000
#define NP 100000
#define NE 200000
#define SCAN_CHUNK 1024

typedef unsigned short u16;
typedef unsigned int u32;
typedef short v8s __attribute__((ext_vector_type(8)));
typedef float f32x4 __attribute__((ext_vector_type(4)));

__device__ __forceinline__ float elu_f(float x) {
  return x > 0.0f ? x : expm1f(x);
}
__device__ __forceinline__ u16 f2bf(float x) {
  u32 u = __float_as_uint(x);
  return (u16)((u + 0x7fffu + ((u >> 16) & 1u)) >> 16);
}
__device__ __forceinline__ float bf2f(u16 h) {
  return __uint_as_float(((u32)h) << 16);
}
__device__ __forceinline__ u32 pk2(float a, float b) {
  return (u32)f2bf(a) | ((u32)f2bf(b) << 16);
}

// ---------------- degree counting (int) ----------------
__global__ void count_deg_i(const int* __restrict__ dst_p, const int* __restrict__ dst_a,
                            int* cnt_p, int* cnt_a) {
  int i = blockIdx.x * blockDim.x + threadIdx.x;
  if (i < NE) atomicAdd(&cnt_p[dst_p[i]], 1);
  else if (i < 2 * NE) atomicAdd(&cnt_a[dst_a[i - NE]], 1);
}

// ---------------- 3-kernel exclusive scan ----------------
__global__ void block_sums_k(const int* __restrict__ cnt, int* __restrict__ bsums, int n) {
  __shared__ int red[256];
  int t = threadIdx.x;
  int base = blockIdx.x * SCAN_CHUNK + t * 4;
  int s = 0;
  #pragma unroll
  for (int i = 0; i < 4; ++i) {
    int idx = base + i;
    if (idx < n) s += cnt[idx];
  }
  red[t] = s;
  __syncthreads();
  for (int off = 128; off > 0; off >>= 1) {
    if (t < off) red[t] += red[t + off];
    __syncthreads();
  }
  if (t == 0) bsums[blockIdx.x] = red[0];
}

__global__ void scan_bsums_k(int* bsums, int nb) {  // nb <= 256, single block
  __shared__ int tmp[256];
  int t = threadIdx.x;
  int orig = (t < nb) ? bsums[t] : 0;
  tmp[t] = orig;
  __syncthreads();
  for (int off = 1; off < 256; off <<= 1) {
    int u = (t >= off) ? tmp[t - off] : 0;
    __syncthreads();
    tmp[t] += u;
    __syncthreads();
  }
  if (t < nb) bsums[t] = tmp[t] - orig;  // exclusive
}

__global__ void scan_final_k(const int* __restrict__ cnt, const int* __restrict__ bsums,
                             int* __restrict__ row_start, int n, int total) {
  __shared__ int red[256];
  int t = threadIdx.x;
  int base = blockIdx.x * SCAN_CHUNK + t * 4;
  int v[4];
  int s = 0;
  #pragma unroll
  for (int i = 0; i < 4; ++i) {
    int idx = base + i;
    v[i] = (idx < n) ? cnt[idx] : 0;
    s += v[i];
  }
  int orig = s;
  red[t] = s;
  __syncthreads();
  for (int off = 1; off < 256; off <<= 1) {
    int u = (t >= off) ? red[t - off] : 0;
    __syncthreads();
    red[t] += u;
    __syncthreads();
  }
  int excl = red[t] - orig + bsums[blockIdx.x];
  #pragma unroll
  for (int i = 0; i < 4; ++i) {
    int idx = base + i;
    if (idx < n) row_start[idx] = excl;
    excl += v[i];
  }
  if (blockIdx.x == 0 && t == 0) row_start[n] = total;
}

__global__ void csr_fill(const int* __restrict__ src, const int* __restrict__ dst,
                         int* cursor, int* __restrict__ csr_src) {
  int e = blockIdx.x * blockDim.x + threadIdx.x;
  if (e < NE) {
    int p = atomicAdd(&cursor[dst[e]], 1);
    csr_src[p] = src[e];
  }
}

// ---------------- f32 -> bf16 bulk convert ----------------
__global__ void to_bf16(const float* __restrict__ in, u16* __restrict__ out, int n4) {
  int i = blockIdx.x * 256 + threadIdx.x;
  if (i >= n4) return;
  float4 v = ((const float4*)in)[i];
  uint2 o;
  o.x = pk2(v.x, v.y);
  o.y = pk2(v.z, v.w);
  *(uint2*)(out + (size_t)i * 4) = o;
}

// ---------------- weight pack: W[256][K] f32 -> Wp[ks][c][lane][8] bf16 ----------------
// element (ks,c,l,j) = W[c*16 + (l&15)][ks*32 + (l>>4)*8 + j]
__global__ void pack_w(const float* __restrict__ W, u16* __restrict__ Wp, int K) {
  int id = blockIdx.x * 256 + threadIdx.x;
  if (id >= K * 32) return;  // (K/32) * 16 * 64
  int l = id & 63;
  int c = (id >> 6) & 15;
  int ks = id >> 10;
  int n = c * 16 + (l & 15);
  int k = ks * 32 + (l >> 4) * 8;
  const float* src = W + (size_t)n * K + k;
  uint4 o;
  o.x = pk2(src[0], src[1]);
  o.y = pk2(src[2], src[3]);
  o.z = pk2(src[4], src[5]);
  o.w = pk2(src[6], src[7]);
  *(uint4*)(Wp + (size_t)id * 8) = o;
}

__global__ void add_bias(const float* __restrict__ a, const float* __restrict__ b,
                         float* __restrict__ o) {
  int i = threadIdx.x;
  o[i] = a[i] + b[i];
}

// ---------------- gather-mean helper (bf16 in/out, f32 accum): one wave per node ----------------
template <int D>
__device__ __forceinline__ void gm_node(const u16* __restrict__ feat, const int* __restrict__ cs,
                                        const int* __restrict__ rs, u16* __restrict__ agg,
                                        int node, int lane) {
  int beg = rs[node], end = rs[node + 1];
  if (D == 256) {
    float a0 = 0.f, a1 = 0.f, a2 = 0.f, a3 = 0.f;
    for (int e = beg; e < end; ++e) {
      int s = cs[e];
      ushort4 u = *(const ushort4*)(feat + (size_t)s * 256 + lane * 4);
      a0 += bf2f(u.x); a1 += bf2f(u.y); a2 += bf2f(u.z); a3 += bf2f(u.w);
    }
    float inv = 1.0f / fmaxf((float)(end - beg), 1.0f);
    uint2 o;
    o.x = pk2(a0 * inv, a1 * inv);
    o.y = pk2(a2 * inv, a3 * inv);
    *(uint2*)(agg + (size_t)node * 256 + lane * 4) = o;
  } else {
    float a0 = 0.f, a1 = 0.f;
    for (int e = beg; e < end; ++e) {
      int s = cs[e];
      ushort2 u = *(const ushort2*)(feat + (size_t)s * 128 + lane * 2);
      a0 += bf2f(u.x); a1 += bf2f(u.y);
    }
    float inv = 1.0f / fmaxf((float)(end - beg), 1.0f);
    *(u32*)(agg + (size_t)node * 128 + lane * 2) = pk2(a0 * inv, a1 * inv);
  }
}

// fused gather for both node types in one dispatch
template <int D1, int D2>
__global__ __launch_bounds__(256) void gather2(
    const u16* __restrict__ f1, const int* __restrict__ cs1, const int* __restrict__ rs1,
    u16* __restrict__ a1, int n1,
    const u16* __restrict__ f2, const int* __restrict__ cs2, const int* __restrict__ rs2,
    u16* __restrict__ a2, int n2) {
  int wid = (blockIdx.x * 256 + threadIdx.x) >> 6;
  int lane = threadIdx.x & 63;
  if (wid < n1) gm_node<D1>(f1, cs1, rs1, a1, wid, lane);
  else if (wid - n1 < n2) gm_node<D2>(f2, cs2, rs2, a2, wid - n1, lane);
}

// ---------------- fused SAGE update, bf16 MFMA, dbuf LDS weights, both sides ----------------
// out[i,:] = elu( agg[i,:] @ Wl^T + x[i,:] @ Wr^T + bias ), Wp = packed [Wl|Wr] contiguous.
// Block: 256 thr = 4 waves (2 row-waves x 2 col-waves); block tile = 64 rows x 128 cols.
// Wave tile: 32 rows (2 row-tiles) x 64 cols (4 c-tiles). acc[2][4] = 32 regs.
// K-chunks of 32: weight chunk 8 KB, double-buffered (2x16KB LDS), stage+xf prefetched.
struct Side {
  const u16* agg;
  const u16* x;
  const u16* Wp;     // packed, (K1+K2)*256 u16
  const float* bias;
  u16* out;
  int M;
  int K1;
  int K2;
};

__global__ __launch_bounds__(256, 4) void sage_fused(Side P, Side A, int nbP) {
  __shared__ __align__(16) u16 ldsw[2][4096];
  int bid = blockIdx.x;
  const Side S = (bid < nbP) ? P : A;
  if (bid >= nbP) bid -= nbP;
  const int rg = bid >> 1, cg = bid & 1;
  const int t = threadIdx.x;
  const int w = t >> 6, l = t & 63;
  const int rw = w & 1, cw = w >> 1;
  const int lr = l & 15, lk = l >> 4;
  const int rowbase = rg * 64 + rw * 32;
  const int ar0 = min(rowbase + lr, S.M - 1);
  const int ar1 = min(rowbase + 16 + lr, S.M - 1);
  const u16* aggr0 = S.agg + (size_t)ar0 * S.K1 + lk * 8;
  const u16* aggr1 = S.agg + (size_t)ar1 * S.K1 + lk * 8;
  const u16* xr0 = S.x + (size_t)ar0 * S.K2 + lk * 8;
  const u16* xr1 = S.x + (size_t)ar1 * S.K2 + lk * 8;
  const int nk = (S.K1 + S.K2) >> 5;
  const uint4* W4 = (const uint4*)S.Wp;

  auto xfrag = [&](int c, int rt) -> v8s {
    int kc = c * 32;
    const u16* p;
    if (kc < S.K1) p = (rt ? aggr1 : aggr0) + kc;
    else p = (rt ? xr1 : xr0) + (kc - S.K1);
    return *(const v8s*)p;
  };

  f32x4 acc[2][4];
  #pragma unroll
  for (int rt = 0; rt < 2; ++rt)
    #pragma unroll
    for (int i = 0; i < 4; ++i) acc[rt][i] = (f32x4){0.f, 0.f, 0.f, 0.f};

  // prologue: stage chunk 0 + load x fragments for chunk 0
  {
    const uint4* cb = W4 + (size_t)cg * 512;
    uint4 s0 = cb[t], s1 = cb[t + 256];
    uint4* lb = (uint4*)ldsw[0];
    lb[t] = s0;
    lb[t + 256] = s1;
  }
  v8s xc0 = xfrag(0, 0);
  v8s xc1 = xfrag(0, 1);
  __syncthreads();

  const u16* lwbase0 = ldsw[0] + (size_t)(cw * 256 + l) * 8;
  const u16* lwbase1 = ldsw[1] + (size_t)(cw * 256 + l) * 8;

  for (int c = 0; c < nk; ++c) {
    const int cur = c & 1;
    const bool more = (c + 1 < nk);
    uint4 n0, n1;
    v8s xn0, xn1;
    if (more) {  // issue next-chunk loads before compute (latency hides under MFMA)
      const uint4* cb = W4 + (size_t)(c + 1) * 1024 + cg * 512;
      n0 = cb[t];
      n1 = cb[t + 256];
      xn0 = xfrag(c + 1, 0);
      xn1 = xfrag(c + 1, 1);
    }
    const u16* lw = cur ? lwbase1 : lwbase0;
    #pragma unroll
    for (int i = 0; i < 4; ++i) {
      v8s wf = *(const v8s*)(lw + i * 512);
      acc[0][i] = __builtin_amdgcn_mfma_f32_16x16x32_bf16(wf, xc0, acc[0][i], 0, 0, 0);
      acc[1][i] = __builtin_amdgcn_mfma_f32_16x16x32_bf16(wf, xc1, acc[1][i], 0, 0, 0);
    }
    if (more) {  // write-late into the other buffer
      uint4* lb = (uint4*)ldsw[cur ^ 1];
      lb[t] = n0;
      lb[t + 256] = n1;
      xc0 = xn0;
      xc1 = xn1;
    }
    __syncthreads();
  }

  // epilogue: bias + ELU + bf16 store
  const int colb = cg * 128 + cw * 64 + lk * 4;
  #pragma unroll
  for (int rt = 0; rt < 2; ++rt) {
    int row = rowbase + rt * 16 + lr;
    if (row < S.M) {
      u16* orow = S.out + (size_t)row * 256 + colb;
      #pragma unroll
      for (int i = 0; i < 4; ++i) {
        f32x4 bv = *(const f32x4*)(S.bias + colb + i * 16);
        float e0 = elu_f(acc[rt][i][0] + bv[0]);
        float e1 = elu_f(acc[rt][i][1] + bv[1]);
        float e2 = elu_f(acc[rt][i][2] + bv[2]);
        float e3 = elu_f(acc[rt][i][3] + bv[3]);
        uint2 o;
        o.x = pk2(e0, e1);
        o.y = pk2(e2, e3);
        *(uint2*)(orow + i * 16) = o;
      }
    }
  }
}

// ---------------- output projection (bf16 author) ----------------
__global__ __launch_bounds__(256) void out_proj(const u16* __restrict__ author,
                                                const float* __restrict__ W,
                                                const float* __restrict__ b,
                                                float* __restrict__ out, int M) {
  __shared__ float ws[10 * 256];
  __shared__ float bs[10];
  int t = threadIdx.x;
  for (int i = t; i < 2560; i += 256) ws[i] = W[i];
  if (t < 10) bs[t] = b[t];
  __syncthreads();
  int wave = t >> 6, lane = t & 63;
  int row = blockIdx.x * 4 + wave;
  if (row >= M) return;
  ushort4 u = *(const ushort4*)(author + (size_t)row * 256 + lane * 4);
  float a0 = bf2f(u.x), a1 = bf2f(u.y), a2 = bf2f(u.z), a3 = bf2f(u.w);
  float p[10];
  #pragma unroll
  for (int n = 0; n < 10; ++n) {
    const float* wv = ws + n * 256 + lane * 4;
    p[n] = a0 * wv[0] + a1 * wv[1] + a2 * wv[2] + a3 * wv[3];
  }
  #pragma unroll
  for (int off = 32; off > 0; off >>= 1) {
    #pragma unroll
    for (int n = 0; n < 10; ++n) p[n] += __shfl_down(p[n], off);
  }
  if (lane == 0) {
    #pragma unroll
    for (int n = 0; n < 10; ++n) out[(size_t)row * 10 + n] = p[n] + bs[n];
  }
}

extern "C" void kernel_launch(void* const* d_in, const int* in_sizes, int n_in,
                              void* d_out, int out_size, void* d_ws, size_t ws_size,
                              hipStream_t stream) {
  const float* x_author = (const float*)d_in[0];
  const float* x_paper  = (const float*)d_in[1];
  const int* ei_a2p = (const int*)d_in[2];
  const int* ei_p2a = (const int*)d_in[3];
  const int* src_ap = ei_a2p;       // author indices
  const int* dst_ap = ei_a2p + NE;  // paper indices
  const int* src_pa = ei_p2a;       // paper indices
  const int* dst_pa = ei_p2a + NE;  // author indices
  const float* Wl0_ap = (const float*)d_in[4];
  const float* bl0_ap = (const float*)d_in[5];
  const float* Wr0_ap = (const float*)d_in[6];
  const float* br0_ap = (const float*)d_in[7];
  const float* Wl0_pa = (const float*)d_in[8];
  const float* bl0_pa = (const float*)d_in[9];
  const float* Wr0_pa = (const float*)d_in[10];
  const float* br0_pa = (const float*)d_in[11];
  const float* Wl_ap = (const float*)d_in[12];
  const float* bl_ap = (const float*)d_in[13];
  const float* Wr_ap = (const float*)d_in[14];
  const float* br_ap = (const float*)d_in[15];
  const float* Wl_pa = (const float*)d_in[16];
  const float* bl_pa = (const float*)d_in[17];
  const float* Wr_pa = (const float*)d_in[18];
  const float* br_pa = (const float*)d_in[19];
  const float* W_out = (const float*)d_in[20];
  const float* b_out = (const float*)d_in[21];
  float* out = (float*)d_out;

  // ---- workspace layout (byte offsets, 256B-aligned chunks) ----
  char* base = (char*)d_ws;
  size_t o = 0;
  auto alloc = [&](size_t bytes) {
    void* p = base + o;
    o += (bytes + 255) & ~(size_t)255;
    return p;
  };
  u16* paper   = (u16*)alloc((size_t)NP * 256 * 2);
  u16* author  = (u16*)alloc((size_t)NA * 256 * 2);
  u16* paper2  = (u16*)alloc((size_t)NP * 256 * 2);
  u16* author2 = (u16*)alloc((size_t)NA * 256 * 2);
  u16* agg_p  = (u16*)alloc((size_t)NP * 256 * 2);
  u16* agg_a  = (u16*)alloc((size_t)NA * 256 * 2);
  u16* xp_bf  = (u16*)alloc((size_t)NP * 256 * 2);
  u16* xa_bf  = (u16*)alloc((size_t)NA * 128 * 2);
  u16* wc0_p = (u16*)alloc((128 + 256) * 256 * 2);        // [Wl0_ap | Wr0_ap]
  u16* wc0_a = (u16*)alloc((256 + 128) * 256 * 2);        // [Wl0_pa | Wr0_pa]
  u16* wc_ap = (u16*)alloc((size_t)2 * 512 * 256 * 2);    // per layer: [Wl | Wr]
  u16* wc_pa = (u16*)alloc((size_t)2 * 512 * 256 * 2);
  float* bias0_ap = (float*)alloc(256 * 4);
  float* bias0_pa = (float*)alloc(256 * 4);
  float* bias_ap  = (float*)alloc(2 * 256 * 4);
  float* bias_pa  = (float*)alloc(2 * 256 * 4);
  int* cnt_p  = (int*)alloc((size_t)(NP + NA) * 4);  // cnt_p + cnt_a contiguous
  int* cnt_a  = cnt_p + NP;
  int* rs_p   = (int*)alloc((size_t)(NP + 1) * 4);
  int* rs_a   = (int*)alloc((size_t)(NA + 1) * 4);
  int* cur_p  = (int*)alloc((size_t)NP * 4);
  int* cur_a  = (int*)alloc((size_t)NA * 4);
  int* csrc_p = (int*)alloc((size_t)NE * 4);
  int* csrc_a = (int*)alloc((size_t)NE * 4);
  int* bsum_p = (int*)alloc(128 * 4);
  int* bsum_a = (int*)alloc(128 * 4);

  const int NBP = (NP + SCAN_CHUNK - 1) / SCAN_CHUNK;  // 98
  const int NBA = (NA + SCAN_CHUNK - 1) / SCAN_CHUNK;  // 49

  // ---- CSR build (once, reused by all 3 layers) ----
  hipMemsetAsync(cnt_p, 0, (size_t)(NP + NA) * 4, stream);
  count_deg_i<<<(2 * NE + 255) / 256, 256, 0, stream>>>(dst_ap, dst_pa, cnt_p, cnt_a);
  block_sums_k<<<NBP, 256, 0, stream>>>(cnt_p, bsum_p, NP);
  block_sums_k<<<NBA, 256, 0, stream>>>(cnt_a, bsum_a, NA);
  scan_bsums_k<<<1, 256, 0, stream>>>(bsum_p, NBP);
  scan_bsums_k<<<1, 256, 0, stream>>>(bsum_a, NBA);
  scan_final_k<<<NBP, 256, 0, stream>>>(cnt_p, bsum_p, rs_p, NP, NE);
  scan_final_k<<<NBA, 256, 0, stream>>>(cnt_a, bsum_a, rs_a, NA, NE);
  hipMemcpyAsync(cur_p, rs_p, (size_t)NP * 4, hipMemcpyDeviceToDevice, stream);
  hipMemcpyAsync(cur_a, rs_a, (size_t)NA * 4, hipMemcpyDeviceToDevice, stream);
  csr_fill<<<(NE + 255) / 256, 256, 0, stream>>>(src_ap, dst_ap, cur_p, csrc_p);
  csr_fill<<<(NE + 255) / 256, 256, 0, stream>>>(src_pa, dst_pa, cur_a, csrc_a);

  // ---- input conversion to bf16 ----
  to_bf16<<<((NP * 256 / 4) + 255) / 256, 256, 0, stream>>>(x_paper, xp_bf, NP * 256 / 4);
  to_bf16<<<((NA * 128 / 4) + 255) / 256, 256, 0, stream>>>(x_author, xa_bf, NA * 128 / 4);

  // ---- weight pack (f32 -> bf16 MFMA-fragment order, [Wl|Wr] contiguous) ----
  pack_w<<<(128 * 32 + 255) / 256, 256, 0, stream>>>(Wl0_ap, wc0_p, 128);
  pack_w<<<(256 * 32 + 255) / 256, 256, 0, stream>>>(Wr0_ap, wc0_p + 128 * 256, 256);
  pack_w<<<(256 * 32 + 255) / 256, 256, 0, stream>>>(Wl0_pa, wc0_a, 256);
  pack_w<<<(128 * 32 + 255) / 256, 256, 0, stream>>>(Wr0_pa, wc0_a + 256 * 256, 128);
  for (int l = 0; l < 2; ++l) {
    pack_w<<<(256 * 32 + 255) / 256, 256, 0, stream>>>(Wl_ap + (size_t)l * 65536, wc_ap + (size_t)l * 131072, 256);
    pack_w<<<(256 * 32 + 255) / 256, 256, 0, stream>>>(Wr_ap + (size_t)l * 65536, wc_ap + (size_t)l * 131072 + 65536, 256);
    pack_w<<<(256 * 32 + 255) / 256, 256, 0, stream>>>(Wl_pa + (size_t)l * 65536, wc_pa + (size_t)l * 131072, 256);
    pack_w<<<(256 * 32 + 255) / 256, 256, 0, stream>>>(Wr_pa + (size_t)l * 65536, wc_pa + (size_t)l * 131072 + 65536, 256);
  }
  add_bias<<<1, 256, 0, stream>>>(bl0_ap, br0_ap, bias0_ap);
  add_bias<<<1, 256, 0, stream>>>(bl0_pa, br0_pa, bias0_pa);
  for (int l = 0; l < 2; ++l) {
    add_bias<<<1, 256, 0, stream>>>(bl_ap + l * 256, br_ap + l * 256, bias_ap + l * 256);
    add_bias<<<1, 256, 0, stream>>>(bl_pa + l * 256, br_pa + l * 256, bias_pa + l * 256);
  }

  const int RGP = (NP + 63) / 64;  // 1563
  const int RGA = (NA + 63) / 64;  // 782
  const int nbP = RGP * 2;         // 3126
  const int grid_sage = nbP + RGA * 2;  // 4690
  const int grid_gath = (NP + NA) / 4;  // 37500

  // ---- layer 0 (author:128, paper:256 inputs) -> paper, author ----
  gather2<128, 256><<<grid_gath, 256, 0, stream>>>(
      xa_bf, csrc_p, rs_p, agg_p, NP, xp_bf, csrc_a, rs_a, agg_a, NA);
  sage_fused<<<grid_sage, 256, 0, stream>>>(
      Side{agg_p, xp_bf, wc0_p, bias0_ap, paper, NP, 128, 256},
      Side{agg_a, xa_bf, wc0_a, bias0_pa, author, NA, 256, 128}, nbP);

  // ---- layer 1: (paper, author) -> (paper2, author2) ----
  gather2<256, 256><<<grid_gath, 256, 0, stream>>>(
      author, csrc_p, rs_p, agg_p, NP, paper, csrc_a, rs_a, agg_a, NA);
  sage_fused<<<grid_sage, 256, 0, stream>>>(
      Side{agg_p, paper, wc_ap, bias_ap, paper2, NP, 256, 256},
      Side{agg_a, author, wc_pa, bias_pa, author2, NA, 256, 256}, nbP);

  // ---- layer 2: (paper2, author2) -> (paper, author) ----
  gather2<256, 256><<<grid_gath, 256, 0, stream>>>(
      author2, csrc_p, rs_p, agg_p, NP, paper2, csrc_a, rs_a, agg_a, NA);
  sage_fused<<<grid_sage, 256, 0, stream>>>(
      Side{agg_p, paper2, wc_ap + 131072, bias_ap + 256, paper, NP, 256, 256},
      Side{agg_a, author2, wc_pa + 131072, bias_pa + 256, author, NA, 256, 256}, nbP);

  // ---- output projection ----
  out_proj<<<(NA + 3) / 4, 256, 0, stream>>>(author, W_out, b_out, out, NA);
}